// Round 10
// baseline (415.059 us; speedup 1.0000x reference)
//
#include <hip/hip_runtime.h>
#include <hip/hip_bf16.h>
#include <hip/hip_fp16.h>

#define NTOT 65536   // T*H*W

typedef __hip_bfloat16 bf16;
typedef _Float16 f16;
typedef f16 f16x4 __attribute__((ext_vector_type(4)));
typedef float f32x4 __attribute__((ext_vector_type(4)));

__device__ __forceinline__ float lo2f(unsigned u) { return __uint_as_float(u << 16); }
__device__ __forceinline__ float hi2f(unsigned u) { return __uint_as_float(u & 0xffff0000u); }
__device__ __forceinline__ ushort f2hs(float f) {
  __half h = __float2half(f);
  return __half_as_ushort(h);
}

// ---------------- K1: 1x1x1 conv as tiled GEMM; output TRANSPOSED [n][ch] f16
__global__ __launch_bounds__(256) void k_qkv(const float* __restrict__ x,
                                             const float* __restrict__ w,
                                             ushort* __restrict__ qkvT) {
  const int n0  = blockIdx.x * 64;
  const int oct = blockIdx.y;           // 0..11
  __shared__ float Wt[64][68];          // [k][oc]
  __shared__ float Xs[64][68];          // [k][n]
  const int tid = threadIdx.x;
  const float4* w4 = (const float4*)w;
#pragma unroll
  for (int i = 0; i < 4; ++i) {
    int idx = tid + i * 256;            // 0..1023
    int oc = idx >> 4, kq = idx & 15;
    float4 wv = w4[(oct * 64 + oc) * 16 + kq];
    Wt[kq * 4 + 0][oc] = wv.x;
    Wt[kq * 4 + 1][oc] = wv.y;
    Wt[kq * 4 + 2][oc] = wv.z;
    Wt[kq * 4 + 3][oc] = wv.w;
    int k = idx >> 4, c4 = idx & 15;
    *(float4*)&Xs[k][c4 * 4] = *(const float4*)(x + k * NTOT + n0 + c4 * 4);
  }
  __syncthreads();
  const int oci = tid >> 4, ni = tid & 15;
  float acc[4][4] = {};
#pragma unroll 8
  for (int k = 0; k < 64; ++k) {
    float4 wf = *(const float4*)&Wt[k][oci * 4];
    float4 xf = *(const float4*)&Xs[k][ni * 4];
    float wa[4] = {wf.x, wf.y, wf.z, wf.w};
    float xa[4] = {xf.x, xf.y, xf.z, xf.w};
#pragma unroll
    for (int a = 0; a < 4; ++a)
#pragma unroll
      for (int b = 0; b < 4; ++b) acc[a][b] = fmaf(wa[a], xa[b], acc[a][b]);
  }
  // transposed store: for each n, 4 consecutive oc as one 8B chunk
#pragma unroll
  for (int b = 0; b < 4; ++b) {
    const int n = n0 + ni * 4 + b;
    ushort4 o;
    o.x = f2hs(acc[0][b]);
    o.y = f2hs(acc[1][b]);
    o.z = f2hs(acc[2][b]);
    o.w = f2hs(acc[3][b]);
    *(ushort4*)(qkvT + (size_t)n * 768 + oct * 64 + oci * 4) = o;
  }
}

// ---------------- K2: grouped 3x3x3 conv as block-diagonal implicit GEMM on MFMA
// cluster = 4 groups = 16 ch. Tile: 4t x 4h x 32w. Halo LDS [t6][h6][w34][ch16] f16.
// Per tap: A_tap (16x16 block-diag weights) x B (shifted halo read) via mfma 16x16x16 f16.
__global__ __launch_bounds__(256) void k_dwconv(const ushort* __restrict__ qkvT,
                                                const float* __restrict__ dww,
                                                bf16* __restrict__ out) {
  const int cl = blockIdx.x;        // 0..47  (fast dim: clusters share spatial halo in L2)
  const int s  = blockIdx.y;        // 0..127 spatial tile
  const int wsel = s & 1, hsel = (s >> 1) & 15, tsel = (s >> 5) & 3;
  const int t0 = tsel * 4, h0 = hsel * 4, w0 = wsel * 32;
  __shared__ __align__(16) ushort xh[6 * 6 * 34 * 16];  // 39168 B
  __shared__ __align__(16) ushort at[27 * 256];         // 13824 B  [tap][oc'][ic']
  const int tid = threadIdx.x;

  // ---- pack A table: at[tap][oc'][ic'] = w if same group else 0
  for (int idx = tid; idx < 27 * 256; idx += 256) {
    int tap = idx >> 8;
    int ocp = (idx >> 4) & 15;
    int icp = idx & 15;
    ushort v = 0;
    if ((icp >> 2) == (ocp >> 2)) {
      int g = cl * 4 + (ocp >> 2);
      v = f2hs(dww[g * 432 + ((ocp & 3) * 4 + (icp & 3)) * 27 + tap]);
    }
    at[idx] = v;
  }
  // ---- stage halo: 36 (t,h) x 34 w chunks of 16ch (32B each), straight copy (no transpose)
  for (int ci = tid; ci < 36 * 34; ci += 256) {
    int wwi = ci % 34;
    int r   = ci / 34;               // 0..35
    int hhi = r % 6, tti = r / 6;
    int T = t0 - 1 + tti, H = h0 - 1 + hhi, W = w0 - 1 + wwi;
    uint4 d0 = {0, 0, 0, 0}, d1 = {0, 0, 0, 0};
    if ((unsigned)T < 16u && (unsigned)H < 64u && (unsigned)W < 64u) {
      const uint4* src = (const uint4*)(qkvT + (size_t)(T * 4096 + H * 64 + W) * 768 + cl * 16);
      d0 = src[0];
      d1 = src[1];
    }
    uint4* dst = (uint4*)(xh + ci * 16);
    dst[0] = d0;
    dst[1] = d1;
  }
  __syncthreads();

  const int lane = tid & 63;
  const int wv   = tid >> 6;        // wave id = t-index within tile
  const int ln15 = lane & 15;       // A: oc' row | B: n col | D: n col
  const int lq   = lane >> 4;       // k-block (4 consecutive ic'/ch)
  const ushort* B0 = xh + ((wv * 6) * 34 + ln15) * 16 + lq * 4;
  const ushort* A0 = at + ln15 * 16 + lq * 4;

  f32x4 acc[8];
#pragma unroll
  for (int i = 0; i < 8; ++i) acc[i] = (f32x4){0.f, 0.f, 0.f, 0.f};

#pragma unroll
  for (int dt = 0; dt < 3; ++dt) {
#pragma unroll
    for (int dh = 0; dh < 3; ++dh) {
#pragma unroll
      for (int dwp = 0; dwp < 3; ++dwp) {
        const int tap = (dt * 3 + dh) * 3 + dwp;
        f16x4 a = *(const f16x4*)(A0 + tap * 256);
        const ushort* bt = B0 + ((dt * 6 + dh) * 34 + dwp) * 16;
#pragma unroll
        for (int ns = 0; ns < 8; ++ns) {
          const int hi = ns >> 1, wh = ns & 1;
          f16x4 b = *(const f16x4*)(bt + (hi * 34 + wh * 16) * 16);
          acc[ns] = __builtin_amdgcn_mfma_f32_16x16x16f16(a, b, acc[ns], 0, 0, 0);
        }
      }
    }
  }
  // ---- epilogue: D row=(lq*4+r)=oc', col=ln15=w-offset
  const int chbase = cl * 16 + lq * 4;
#pragma unroll
  for (int ns = 0; ns < 8; ++ns) {
    const int hi = ns >> 1, wh = ns & 1;
    const int n = (t0 + wv) * 4096 + (h0 + hi) * 64 + w0 + wh * 16 + ln15;
#pragma unroll
    for (int r = 0; r < 4; ++r)
      out[(size_t)(chbase + r) * NTOT + n] = __float2bfloat16(acc[ns][r]);
  }
}

// ---------------- K3: partial gram S[c][d] = sum_n q[c][n]k[d][n], plus sum q^2, k^2
__global__ __launch_bounds__(256) void k_attn_part(const bf16* __restrict__ dwout,
                                                   float* __restrict__ pS,
                                                   float* __restrict__ pQ,
                                                   float* __restrict__ pK) {
  const int head = blockIdx.y;
  const int chunk = blockIdx.x;   // 0..127, each 512 n
  const int tid = threadIdx.x;
  const ushort* qb = (const ushort*)dwout + (head * 64) * (size_t)NTOT;
  const ushort* kb = (const ushort*)dwout + (256 + head * 64) * (size_t)NTOT;
  __shared__ float lq[64][68];   // 17.4 KB
  __shared__ float lk[64][68];
  const int ci = tid & 15, di = tid >> 4;
  float acc[4][4] = {};
  float qq = 0.f, kk = 0.f;
  for (int s = 0; s < 8; ++s) {
    const int nb = chunk * 512 + s * 64;
    __syncthreads();
#pragma unroll
    for (int i = 0; i < 2; ++i) {
      int f = tid + i * 256;      // 0..511
      int c = f >> 3, n8 = f & 7;
      uint4 qv = *(const uint4*)(qb + c * NTOT + nb + n8 * 8);
      uint4 kv = *(const uint4*)(kb + c * NTOT + nb + n8 * 8);
      int r = n8 * 8;
      lq[r + 0][c] = lo2f(qv.x); lq[r + 1][c] = hi2f(qv.x);
      lq[r + 2][c] = lo2f(qv.y); lq[r + 3][c] = hi2f(qv.y);
      lq[r + 4][c] = lo2f(qv.z); lq[r + 5][c] = hi2f(qv.z);
      lq[r + 6][c] = lo2f(qv.w); lq[r + 7][c] = hi2f(qv.w);
      lk[r + 0][c] = lo2f(kv.x); lk[r + 1][c] = hi2f(kv.x);
      lk[r + 2][c] = lo2f(kv.y); lk[r + 3][c] = hi2f(kv.y);
      lk[r + 4][c] = lo2f(kv.z); lk[r + 5][c] = hi2f(kv.z);
      lk[r + 6][c] = lo2f(kv.w); lk[r + 7][c] = hi2f(kv.w);
    }
    __syncthreads();
#pragma unroll 4
    for (int j = 0; j < 64; ++j) {
      float4 q4 = *(const float4*)&lq[j][ci * 4];
      float4 k4 = *(const float4*)&lk[j][di * 4];
      float qa[4] = {q4.x, q4.y, q4.z, q4.w};
      float ka[4] = {k4.x, k4.y, k4.z, k4.w};
#pragma unroll
      for (int a = 0; a < 4; ++a)
#pragma unroll
        for (int b = 0; b < 4; ++b) acc[a][b] = fmaf(qa[a], ka[b], acc[a][b]);
    }
    if (tid < 64) {
#pragma unroll 4
      for (int j = 0; j < 64; ++j) { float v = lq[j][tid]; qq = fmaf(v, v, qq); }
    } else if (tid < 128) {
#pragma unroll 4
      for (int j = 0; j < 64; ++j) { float v = lk[j][tid - 64]; kk = fmaf(v, v, kk); }
    }
  }
  float* ps = pS + (head * 128 + chunk) * 4096;
#pragma unroll
  for (int a = 0; a < 4; ++a) {
    float4 v4 = make_float4(acc[a][0], acc[a][1], acc[a][2], acc[a][3]);
    *(float4*)(ps + (ci * 4 + a) * 64 + di * 4) = v4;
  }
  if (tid < 64) pQ[(head * 128 + chunk) * 64 + tid] = qq;
  else if (tid < 128) pK[(head * 128 + chunk) * 64 + (tid - 64)] = kk;
}

// ---------------- K4a: reduce partials, normalize, temperature, softmax -> A[h][c][d]
__global__ __launch_bounds__(256) void k_softmax(const float* __restrict__ pS,
                                                 const float* __restrict__ pQ,
                                                 const float* __restrict__ pK,
                                                 const float* __restrict__ temp,
                                                 float* __restrict__ A) {
  const int head = blockIdx.x;
  const int tid = threadIdx.x;
  __shared__ float rq[64], rk[64];
  if (tid < 64) {
    float s = 0.f;
    for (int ch = 0; ch < 128; ++ch) s += pQ[(head * 128 + ch) * 64 + tid];
    rq[tid] = 1.f / fmaxf(sqrtf(s), 1e-12f);
  } else if (tid < 128) {
    float s = 0.f;
    for (int ch = 0; ch < 128; ++ch) s += pK[(head * 128 + ch) * 64 + (tid - 64)];
    rk[tid - 64] = 1.f / fmaxf(sqrtf(s), 1e-12f);
  }
  __syncthreads();
  const int c = tid >> 2, r = tid & 3;
  float4 a0 = {0,0,0,0}, a1 = {0,0,0,0}, a2 = {0,0,0,0}, a3 = {0,0,0,0};
  const float* base = pS + head * 128 * 4096 + c * 64 + r * 16;
  for (int ch = 0; ch < 128; ++ch) {
    const float* p = base + ch * 4096;
    float4 b0 = *(const float4*)(p + 0);
    float4 b1 = *(const float4*)(p + 4);
    float4 b2 = *(const float4*)(p + 8);
    float4 b3 = *(const float4*)(p + 12);
    a0.x += b0.x; a0.y += b0.y; a0.z += b0.z; a0.w += b0.w;
    a1.x += b1.x; a1.y += b1.y; a1.z += b1.z; a1.w += b1.w;
    a2.x += b2.x; a2.y += b2.y; a2.z += b2.z; a2.w += b2.w;
    a3.x += b3.x; a3.y += b3.y; a3.z += b3.z; a3.w += b3.w;
  }
  float v[16] = {a0.x, a0.y, a0.z, a0.w, a1.x, a1.y, a1.z, a1.w,
                 a2.x, a2.y, a2.z, a2.w, a3.x, a3.y, a3.z, a3.w};
  const float tmp = temp[head];
  const float rqc = rq[c];
#pragma unroll
  for (int dd = 0; dd < 16; ++dd) v[dd] = v[dd] * rqc * rk[r * 16 + dd] * tmp;
  float m = v[0];
#pragma unroll
  for (int dd = 1; dd < 16; ++dd) m = fmaxf(m, v[dd]);
  m = fmaxf(m, __shfl_xor(m, 1));
  m = fmaxf(m, __shfl_xor(m, 2));
  float s = 0.f;
#pragma unroll
  for (int dd = 0; dd < 16; ++dd) { v[dd] = expf(v[dd] - m); s += v[dd]; }
  s += __shfl_xor(s, 1);
  s += __shfl_xor(s, 2);
  const float inv = 1.f / s;
  float* ao = A + head * 4096 + c * 64 + r * 16;
#pragma unroll
  for (int q4 = 0; q4 < 4; ++q4) {
    float4 o = make_float4(v[q4*4+0]*inv, v[q4*4+1]*inv, v[q4*4+2]*inv, v[q4*4+3]*inv);
    *(float4*)(ao + q4 * 4) = o;
  }
}

// ---------------- K4b: fold proj into attn:  Mt[h*64+d][oc] = sum_c pw[oc][h*64+c]*A[h][c][d]
__global__ __launch_bounds__(64) void k_mt(const float* __restrict__ pw,
                                           const float* __restrict__ A,
                                           float* __restrict__ Mt) {
  const int hd = blockIdx.x;   // 0..255
  const int h = hd >> 6, d = hd & 63;
  const int oc = threadIdx.x;  // 0..63
  float s = 0.f;
  for (int c = 0; c < 64; ++c)
    s = fmaf(pw[oc * 256 + h * 64 + c], A[(h * 64 + c) * 64 + d], s);
  Mt[hd * 64 + oc] = s;
}

// ---------------- K5: y[oc][n] = sum_hd Mt[hd][oc] * v[hd][n]  (PV + proj fused)
__global__ __launch_bounds__(256) void k_pv(const bf16* __restrict__ dwout,
                                            const float* __restrict__ Mt,
                                            float* __restrict__ y) {
  const int n0 = blockIdx.x * 64;
  const ushort* vb = (const ushort*)dwout + 512 * (size_t)NTOT;
  __shared__ float lv[256][64];   // 64 KB
  const int tid = threadIdx.x;
#pragma unroll
  for (int i = 0; i < 8; ++i) {
    int f = tid + i * 256;        // 0..2047
    int hd = f >> 3, n8 = f & 7;
    uint4 v = *(const uint4*)(vb + hd * NTOT + n0 + n8 * 8);
    float4 a = make_float4(lo2f(v.x), hi2f(v.x), lo2f(v.y), hi2f(v.y));
    float4 b = make_float4(lo2f(v.z), hi2f(v.z), lo2f(v.w), hi2f(v.w));
    *(float4*)&lv[hd][n8 * 8]     = a;
    *(float4*)&lv[hd][n8 * 8 + 4] = b;
  }
  __syncthreads();
  const int oci = tid >> 4, ni = tid & 15;
  float acc[4][4] = {};
#pragma unroll 4
  for (int k = 0; k < 256; ++k) {
    float4 mv = *(const float4*)(Mt + k * 64 + oci * 4);
    float4 vv = *(const float4*)&lv[k][ni * 4];
    float ma[4] = {mv.x, mv.y, mv.z, mv.w};
    float va[4] = {vv.x, vv.y, vv.z, vv.w};
#pragma unroll
    for (int a = 0; a < 4; ++a)
#pragma unroll
      for (int b = 0; b < 4; ++b) acc[a][b] = fmaf(ma[a], va[b], acc[a][b]);
  }
#pragma unroll
  for (int a = 0; a < 4; ++a) {
    float4 o = make_float4(acc[a][0], acc[a][1], acc[a][2], acc[a][3]);
    *(float4*)(y + (oci * 4 + a) * NTOT + n0 + ni * 4) = o;
  }
}

extern "C" void kernel_launch(void* const* d_in, const int* in_sizes, int n_in,
                              void* d_out, int out_size, void* d_ws, size_t ws_size,
                              hipStream_t stream) {
  const float* x      = (const float*)d_in[0];
  const float* qkv_w  = (const float*)d_in[1];
  const float* dw_w   = (const float*)d_in[2];
  const float* proj_w = (const float*)d_in[3];
  const float* temp   = (const float*)d_in[4];
  float* out = (float*)d_out;

  char* w8 = (char*)d_ws;
  ushort* qkvT = (ushort*)(w8);                        // [n][768] f16 = 100,663,296 B
  bf16*  dwout = (bf16*)(w8 + 100663296ull);           // [768][n] bf16 = 100,663,296 B
  float* pS    = (float*)(w8 + 201326592ull);          // 4*128*4096 f32 = 8,388,608 B
  float* pQ    = (float*)(w8 + 209715200ull);          // 32768 f32
  float* pK    = (float*)(w8 + 209846272ull);          // 32768 f32
  float* A     = (float*)(w8 + 209977344ull);          // 16384 f32
  float* Mt    = (float*)(w8 + 210042880ull);          // 16384 f32
  // total 210,108,416 B

  k_qkv<<<dim3(1024, 12), 256, 0, stream>>>(x, qkv_w, qkvT);
  k_dwconv<<<dim3(48, 128), 256, 0, stream>>>(qkvT, dw_w, dwout);
  k_attn_part<<<dim3(128, 4), 256, 0, stream>>>(dwout, pS, pQ, pK);
  k_softmax<<<4, 256, 0, stream>>>(pS, pQ, pK, temp, A);
  k_mt<<<256, 64, 0, stream>>>(proj_w, A, Mt);
  k_pv<<<1024, 256, 0, stream>>>(dwout, Mt, out);
}

// Round 11
// 312.424 us; speedup vs baseline: 1.3285x; 1.3285x over previous
//
#include <hip/hip_runtime.h>
#include <hip/hip_bf16.h>
#include <hip/hip_fp16.h>

#define NTOT 65536   // T*H*W

typedef __hip_bfloat16 bf16;
typedef _Float16 f16;
typedef f16 f16x4 __attribute__((ext_vector_type(4)));
typedef float f32x4 __attribute__((ext_vector_type(4)));

__device__ __forceinline__ float lo2f(unsigned u) { return __uint_as_float(u << 16); }
__device__ __forceinline__ float hi2f(unsigned u) { return __uint_as_float(u & 0xffff0000u); }
__device__ __forceinline__ ushort f2hs(float f) {
  __half h = __float2half(f);
  return __half_as_ushort(h);
}

// ---------------- K1: 1x1x1 conv as tiled GEMM; output qkvT[cluster][n][16ch] f16
__global__ __launch_bounds__(256) void k_qkv(const float* __restrict__ x,
                                             const float* __restrict__ w,
                                             ushort* __restrict__ qkvT) {
  const int n0  = blockIdx.x * 64;
  const int oct = blockIdx.y;           // 0..11 (64-oc chunk = 4 clusters)
  __shared__ float Wt[64][68];          // [k][oc]
  __shared__ float Xs[64][68];          // [k][n]
  const int tid = threadIdx.x;
  const float4* w4 = (const float4*)w;
#pragma unroll
  for (int i = 0; i < 4; ++i) {
    int idx = tid + i * 256;            // 0..1023
    int oc = idx >> 4, kq = idx & 15;
    float4 wv = w4[(oct * 64 + oc) * 16 + kq];
    Wt[kq * 4 + 0][oc] = wv.x;
    Wt[kq * 4 + 1][oc] = wv.y;
    Wt[kq * 4 + 2][oc] = wv.z;
    Wt[kq * 4 + 3][oc] = wv.w;
    int k = idx >> 4, c4 = idx & 15;
    *(float4*)&Xs[k][c4 * 4] = *(const float4*)(x + k * NTOT + n0 + c4 * 4);
  }
  __syncthreads();
  // oci fast within wave -> stores are 32B-contiguous per 4-lane group
  const int oci = tid & 15, ni = tid >> 4;
  float acc[4][4] = {};
#pragma unroll 8
  for (int k = 0; k < 64; ++k) {
    float4 wf = *(const float4*)&Wt[k][oci * 4];
    float4 xf = *(const float4*)&Xs[k][ni * 4];
    float wa[4] = {wf.x, wf.y, wf.z, wf.w};
    float xa[4] = {xf.x, xf.y, xf.z, xf.w};
#pragma unroll
    for (int a = 0; a < 4; ++a)
#pragma unroll
      for (int b = 0; b < 4; ++b) acc[a][b] = fmaf(wa[a], xa[b], acc[a][b]);
  }
  const size_t clbase = (size_t)(oct * 4 + (oci >> 2)) * NTOT * 16 + (oci & 3) * 4;
#pragma unroll
  for (int b = 0; b < 4; ++b) {
    const int n = n0 + ni * 4 + b;
    ushort4 o;
    o.x = f2hs(acc[0][b]);
    o.y = f2hs(acc[1][b]);
    o.z = f2hs(acc[2][b]);
    o.w = f2hs(acc[3][b]);
    *(ushort4*)(qkvT + clbase + (size_t)n * 16) = o;
  }
}

// ---------------- K2: grouped 3x3x3 conv, block-diag implicit GEMM on MFMA
// Tile 4t x 8h x 16w per cluster (16 ch). Halo [6][10][18][16ch] f16, ch-rotated
// by (W>>2)&3 (bank spread). A-table compressed to diagonal blocks (3456B).
__global__ __launch_bounds__(256, 4) void k_dwconv(const ushort* __restrict__ qkvT,
                                                   const float* __restrict__ dww,
                                                   bf16* __restrict__ out) {
  const int cl = blockIdx.x;        // 0..47
  const int s  = blockIdx.y;        // 0..127
  const int wsel = s & 3, hsel = (s >> 2) & 7, tsel = s >> 5;
  const int t0 = tsel * 4, h0 = hsel * 8, w0 = wsel * 16;
  __shared__ __align__(16) ushort xh[6 * 10 * 18 * 16];  // 34560 B
  __shared__ __align__(16) ushort at[27 * 64];           //  3456 B [tap][p16][ic4]
  const int tid = threadIdx.x;

  // ---- A-table: only diagonal 4x4 blocks. p = (g'<<2)|oc
  for (int idx = tid; idx < 27 * 64; idx += 256) {
    int tap = idx >> 6;
    int p   = (idx >> 2) & 15;
    int ic  = idx & 3;
    at[idx] = f2hs(dww[(cl * 4 + (p >> 2)) * 432 + ((p & 3) * 4 + ic) * 27 + tap]);
  }
  // ---- halo staging: 1080 chunks of 16ch (32B), coalesced 576B runs, rotated store
  const ushort* cb = qkvT + (size_t)cl * (NTOT * 16);
  for (int ci = tid; ci < 1080; ci += 256) {
    int W = ci % 18;
    int r = ci / 18;
    int H = r % 10;
    int T = r / 10;
    int Tg = t0 - 1 + T, Hg = h0 - 1 + H, Wg = w0 - 1 + W;
    uint4 d0 = {0, 0, 0, 0}, d1 = {0, 0, 0, 0};
    if ((unsigned)Tg < 16u && (unsigned)Hg < 64u && (unsigned)Wg < 64u) {
      const uint4* src = (const uint4*)(cb + (size_t)(Tg * 4096 + Hg * 64 + Wg) * 16);
      d0 = src[0];
      d1 = src[1];
    }
    const int rot = (W >> 2) & 3;
    uint2* dst = (uint2*)(xh + ci * 16);
    uint2 u0 = {d0.x, d0.y}, u1 = {d0.z, d0.w}, u2 = {d1.x, d1.y}, u3 = {d1.z, d1.w};
    dst[(0 + rot) & 3] = u0;
    dst[(1 + rot) & 3] = u1;
    dst[(2 + rot) & 3] = u2;
    dst[(3 + rot) & 3] = u3;
  }
  __syncthreads();

  const int lane = tid & 63;
  const int wv   = tid >> 6;        // wave id = t-offset 0..3
  const int ln15 = lane & 15;
  const int lq   = lane >> 4;       // 4-ch block
  const bool diag = (lq == (ln15 >> 2));
  // per-lane rotated read offsets for dwp = 0,1,2 (ushort units)
  const ushort* bp[3];
#pragma unroll
  for (int dwp = 0; dwp < 3; ++dwp) {
    const int Wl = ln15 + dwp;
    const int slot = (lq + (Wl >> 2)) & 3;
    bp[dwp] = xh + wv * 2880 + Wl * 16 + slot * 4;
  }
  const f16x4 z4 = {};

  f32x4 acc[8];
#pragma unroll
  for (int i = 0; i < 8; ++i) acc[i] = (f32x4){0.f, 0.f, 0.f, 0.f};

#pragma unroll
  for (int dt = 0; dt < 3; ++dt) {
#pragma unroll
    for (int dh = 0; dh < 3; ++dh) {
#pragma unroll
      for (int dwp = 0; dwp < 3; ++dwp) {
        const int tap = (dt * 3 + dh) * 3 + dwp;
        f16x4 a = *(const f16x4*)(at + tap * 64 + ln15 * 4);
        if (!diag) a = z4;
#pragma unroll
        for (int hi = 0; hi < 8; ++hi) {
          f16x4 b = *(const f16x4*)(bp[dwp] + (dt * 10 + dh + hi) * 288);
          acc[hi] = __builtin_amdgcn_mfma_f32_16x16x16f16(a, b, acc[hi], 0, 0, 0);
        }
      }
    }
  }
  // ---- epilogue: D row=(lq*4+r)=ch, col=ln15=w
  const int chbase = cl * 16 + lq * 4;
#pragma unroll
  for (int hi = 0; hi < 8; ++hi) {
    const int n = (t0 + wv) * 4096 + (h0 + hi) * 64 + w0 + ln15;
#pragma unroll
    for (int r = 0; r < 4; ++r)
      out[(size_t)(chbase + r) * NTOT + n] = __float2bfloat16(acc[hi][r]);
  }
}

// ---------------- K3: partial gram S[c][d] = sum_n q[c][n]k[d][n], plus sum q^2, k^2
__global__ __launch_bounds__(256) void k_attn_part(const bf16* __restrict__ dwout,
                                                   float* __restrict__ pS,
                                                   float* __restrict__ pQ,
                                                   float* __restrict__ pK) {
  const int head = blockIdx.y;
  const int chunk = blockIdx.x;   // 0..127, each 512 n
  const int tid = threadIdx.x;
  const ushort* qb = (const ushort*)dwout + (head * 64) * (size_t)NTOT;
  const ushort* kb = (const ushort*)dwout + (256 + head * 64) * (size_t)NTOT;
  __shared__ float lq[64][68];   // 17.4 KB
  __shared__ float lk[64][68];
  const int ci = tid & 15, di = tid >> 4;
  float acc[4][4] = {};
  float qq = 0.f, kk = 0.f;
  for (int s = 0; s < 8; ++s) {
    const int nb = chunk * 512 + s * 64;
    __syncthreads();
#pragma unroll
    for (int i = 0; i < 2; ++i) {
      int f = tid + i * 256;      // 0..511
      int c = f >> 3, n8 = f & 7;
      uint4 qv = *(const uint4*)(qb + c * NTOT + nb + n8 * 8);
      uint4 kv = *(const uint4*)(kb + c * NTOT + nb + n8 * 8);
      int r = n8 * 8;
      lq[r + 0][c] = lo2f(qv.x); lq[r + 1][c] = hi2f(qv.x);
      lq[r + 2][c] = lo2f(qv.y); lq[r + 3][c] = hi2f(qv.y);
      lq[r + 4][c] = lo2f(qv.z); lq[r + 5][c] = hi2f(qv.z);
      lq[r + 6][c] = lo2f(qv.w); lq[r + 7][c] = hi2f(qv.w);
      lk[r + 0][c] = lo2f(kv.x); lk[r + 1][c] = hi2f(kv.x);
      lk[r + 2][c] = lo2f(kv.y); lk[r + 3][c] = hi2f(kv.y);
      lk[r + 4][c] = lo2f(kv.z); lk[r + 5][c] = hi2f(kv.z);
      lk[r + 6][c] = lo2f(kv.w); lk[r + 7][c] = hi2f(kv.w);
    }
    __syncthreads();
#pragma unroll 4
    for (int j = 0; j < 64; ++j) {
      float4 q4 = *(const float4*)&lq[j][ci * 4];
      float4 k4 = *(const float4*)&lk[j][di * 4];
      float qa[4] = {q4.x, q4.y, q4.z, q4.w};
      float ka[4] = {k4.x, k4.y, k4.z, k4.w};
#pragma unroll
      for (int a = 0; a < 4; ++a)
#pragma unroll
        for (int b = 0; b < 4; ++b) acc[a][b] = fmaf(qa[a], ka[b], acc[a][b]);
    }
    if (tid < 64) {
#pragma unroll 4
      for (int j = 0; j < 64; ++j) { float v = lq[j][tid]; qq = fmaf(v, v, qq); }
    } else if (tid < 128) {
#pragma unroll 4
      for (int j = 0; j < 64; ++j) { float v = lk[j][tid - 64]; kk = fmaf(v, v, kk); }
    }
  }
  float* ps = pS + (head * 128 + chunk) * 4096;
#pragma unroll
  for (int a = 0; a < 4; ++a) {
    float4 v4 = make_float4(acc[a][0], acc[a][1], acc[a][2], acc[a][3]);
    *(float4*)(ps + (ci * 4 + a) * 64 + di * 4) = v4;
  }
  if (tid < 64) pQ[(head * 128 + chunk) * 64 + tid] = qq;
  else if (tid < 128) pK[(head * 128 + chunk) * 64 + (tid - 64)] = kk;
}

// ---------------- K4a: reduce partials, normalize, temperature, softmax -> A[h][c][d]
__global__ __launch_bounds__(256) void k_softmax(const float* __restrict__ pS,
                                                 const float* __restrict__ pQ,
                                                 const float* __restrict__ pK,
                                                 const float* __restrict__ temp,
                                                 float* __restrict__ A) {
  const int head = blockIdx.x;
  const int tid = threadIdx.x;
  __shared__ float rq[64], rk[64];
  if (tid < 64) {
    float s = 0.f;
    for (int ch = 0; ch < 128; ++ch) s += pQ[(head * 128 + ch) * 64 + tid];
    rq[tid] = 1.f / fmaxf(sqrtf(s), 1e-12f);
  } else if (tid < 128) {
    float s = 0.f;
    for (int ch = 0; ch < 128; ++ch) s += pK[(head * 128 + ch) * 64 + (tid - 64)];
    rk[tid - 64] = 1.f / fmaxf(sqrtf(s), 1e-12f);
  }
  __syncthreads();
  const int c = tid >> 2, r = tid & 3;
  float4 a0 = {0,0,0,0}, a1 = {0,0,0,0}, a2 = {0,0,0,0}, a3 = {0,0,0,0};
  const float* base = pS + head * 128 * 4096 + c * 64 + r * 16;
  for (int ch = 0; ch < 128; ++ch) {
    const float* p = base + ch * 4096;
    float4 b0 = *(const float4*)(p + 0);
    float4 b1 = *(const float4*)(p + 4);
    float4 b2 = *(const float4*)(p + 8);
    float4 b3 = *(const float4*)(p + 12);
    a0.x += b0.x; a0.y += b0.y; a0.z += b0.z; a0.w += b0.w;
    a1.x += b1.x; a1.y += b1.y; a1.z += b1.z; a1.w += b1.w;
    a2.x += b2.x; a2.y += b2.y; a2.z += b2.z; a2.w += b2.w;
    a3.x += b3.x; a3.y += b3.y; a3.z += b3.z; a3.w += b3.w;
  }
  float v[16] = {a0.x, a0.y, a0.z, a0.w, a1.x, a1.y, a1.z, a1.w,
                 a2.x, a2.y, a2.z, a2.w, a3.x, a3.y, a3.z, a3.w};
  const float tmp = temp[head];
  const float rqc = rq[c];
#pragma unroll
  for (int dd = 0; dd < 16; ++dd) v[dd] = v[dd] * rqc * rk[r * 16 + dd] * tmp;
  float m = v[0];
#pragma unroll
  for (int dd = 1; dd < 16; ++dd) m = fmaxf(m, v[dd]);
  m = fmaxf(m, __shfl_xor(m, 1));
  m = fmaxf(m, __shfl_xor(m, 2));
  float s = 0.f;
#pragma unroll
  for (int dd = 0; dd < 16; ++dd) { v[dd] = expf(v[dd] - m); s += v[dd]; }
  s += __shfl_xor(s, 1);
  s += __shfl_xor(s, 2);
  const float inv = 1.f / s;
  float* ao = A + head * 4096 + c * 64 + r * 16;
#pragma unroll
  for (int q4 = 0; q4 < 4; ++q4) {
    float4 o = make_float4(v[q4*4+0]*inv, v[q4*4+1]*inv, v[q4*4+2]*inv, v[q4*4+3]*inv);
    *(float4*)(ao + q4 * 4) = o;
  }
}

// ---------------- K4b: fold proj into attn:  Mt[h*64+d][oc] = sum_c pw[oc][h*64+c]*A[h][c][d]
__global__ __launch_bounds__(64) void k_mt(const float* __restrict__ pw,
                                           const float* __restrict__ A,
                                           float* __restrict__ Mt) {
  const int hd = blockIdx.x;   // 0..255
  const int h = hd >> 6, d = hd & 63;
  const int oc = threadIdx.x;  // 0..63
  float s = 0.f;
  for (int c = 0; c < 64; ++c)
    s = fmaf(pw[oc * 256 + h * 64 + c], A[(h * 64 + c) * 64 + d], s);
  Mt[hd * 64 + oc] = s;
}

// ---------------- K5: y[oc][n] = sum_hd Mt[hd][oc] * v[hd][n]  (PV + proj fused)
__global__ __launch_bounds__(256) void k_pv(const bf16* __restrict__ dwout,
                                            const float* __restrict__ Mt,
                                            float* __restrict__ y) {
  const int n0 = blockIdx.x * 64;
  const ushort* vb = (const ushort*)dwout + 512 * (size_t)NTOT;
  __shared__ float lv[256][64];   // 64 KB
  const int tid = threadIdx.x;
#pragma unroll
  for (int i = 0; i < 8; ++i) {
    int f = tid + i * 256;        // 0..2047
    int hd = f >> 3, n8 = f & 7;
    uint4 v = *(const uint4*)(vb + hd * NTOT + n0 + n8 * 8);
    float4 a = make_float4(lo2f(v.x), hi2f(v.x), lo2f(v.y), hi2f(v.y));
    float4 b = make_float4(lo2f(v.z), hi2f(v.z), lo2f(v.w), hi2f(v.w));
    *(float4*)&lv[hd][n8 * 8]     = a;
    *(float4*)&lv[hd][n8 * 8 + 4] = b;
  }
  __syncthreads();
  const int oci = tid >> 4, ni = tid & 15;
  float acc[4][4] = {};
#pragma unroll 4
  for (int k = 0; k < 256; ++k) {
    float4 mv = *(const float4*)(Mt + k * 64 + oci * 4);
    float4 vv = *(const float4*)&lv[k][ni * 4];
    float ma[4] = {mv.x, mv.y, mv.z, mv.w};
    float va[4] = {vv.x, vv.y, vv.z, vv.w};
#pragma unroll
    for (int a = 0; a < 4; ++a)
#pragma unroll
      for (int b = 0; b < 4; ++b) acc[a][b] = fmaf(ma[a], va[b], acc[a][b]);
  }
#pragma unroll
  for (int a = 0; a < 4; ++a) {
    float4 o = make_float4(acc[a][0], acc[a][1], acc[a][2], acc[a][3]);
    *(float4*)(y + (oci * 4 + a) * NTOT + n0 + ni * 4) = o;
  }
}

extern "C" void kernel_launch(void* const* d_in, const int* in_sizes, int n_in,
                              void* d_out, int out_size, void* d_ws, size_t ws_size,
                              hipStream_t stream) {
  const float* x      = (const float*)d_in[0];
  const float* qkv_w  = (const float*)d_in[1];
  const float* dw_w   = (const float*)d_in[2];
  const float* proj_w = (const float*)d_in[3];
  const float* temp   = (const float*)d_in[4];
  float* out = (float*)d_out;

  char* w8 = (char*)d_ws;
  ushort* qkvT = (ushort*)(w8);                        // [48][65536][16] f16 = 100,663,296 B
  bf16*  dwout = (bf16*)(w8 + 100663296ull);           // [768][n] bf16 = 100,663,296 B
  float* pS    = (float*)(w8 + 201326592ull);          // 4*128*4096 f32 = 8,388,608 B
  float* pQ    = (float*)(w8 + 209715200ull);          // 32768 f32
  float* pK    = (float*)(w8 + 209846272ull);          // 32768 f32
  float* A     = (float*)(w8 + 209977344ull);          // 16384 f32
  float* Mt    = (float*)(w8 + 210042880ull);          // 16384 f32
  // total 210,108,416 B

  k_qkv<<<dim3(1024, 12), 256, 0, stream>>>(x, qkv_w, qkvT);
  k_dwconv<<<dim3(48, 128), 256, 0, stream>>>(qkvT, dw_w, dwout);
  k_attn_part<<<dim3(128, 4), 256, 0, stream>>>(dwout, pS, pQ, pK);
  k_softmax<<<4, 256, 0, stream>>>(pS, pQ, pK, temp, A);
  k_mt<<<256, 64, 0, stream>>>(proj_w, A, Mt);
  k_pv<<<1024, 256, 0, stream>>>(dwout, Mt, out);
}

// Round 12
// 243.334 us; speedup vs baseline: 1.7057x; 1.2839x over previous
//
#include <hip/hip_runtime.h>
#include <hip/hip_bf16.h>
#include <hip/hip_fp16.h>

#define NTOT 65536   // T*H*W

typedef __hip_bfloat16 bf16;
typedef _Float16 f16;
typedef f16 f16x4 __attribute__((ext_vector_type(4)));
typedef float f32x4 __attribute__((ext_vector_type(4)));

__device__ __forceinline__ float lo2f(unsigned u) { return __uint_as_float(u << 16); }
__device__ __forceinline__ float hi2f(unsigned u) { return __uint_as_float(u & 0xffff0000u); }
__device__ __forceinline__ ushort f2hs(float f) {
  __half h = __float2half(f);
  return __half_as_ushort(h);
}

// ---------------- K1: 1x1x1 conv as MFMA GEMM; qkvT[cluster][n][16ch] f16
// block: 64 oc x 64 n, K=64. W in LDS [64oc][72] f16; X in LDS [kb16][n64][8] f16
// (k-quad per entry, slot rotated by kb&1 for bank coverage).
__global__ __launch_bounds__(256) void k_qkv(const float* __restrict__ x,
                                             const float* __restrict__ w,
                                             ushort* __restrict__ qkvT) {
  const int n0  = blockIdx.x * 64;
  const int oct = blockIdx.y;           // 0..11 (64-oc chunk = 4 clusters)
  __shared__ __align__(16) ushort wt[64 * 72];     // 9216 B
  __shared__ __align__(16) ushort xb[16 * 64 * 8]; // 16384 B
  const int tid = threadIdx.x;
  const float4* w4 = (const float4*)w;
#pragma unroll
  for (int i = 0; i < 4; ++i) {
    const int idx = tid + i * 256;      // 0..1023
    {
      // W: oc row, 4 consecutive k per chunk
      const int oc = idx >> 4, kq = idx & 15;
      float4 wv = w4[(oct * 64 + oc) * 16 + kq];
      ushort4 o;
      o.x = f2hs(wv.x); o.y = f2hs(wv.y); o.z = f2hs(wv.z); o.w = f2hs(wv.w);
      *(ushort4*)(wt + oc * 72 + kq * 4) = o;
    }
    {
      // X: k row, 4 consecutive n per chunk -> scatter into k-quad entries
      const int k = idx >> 4, nq = idx & 15;
      const int kb = k >> 2, j = k & 3;
      float4 xv = *(const float4*)(x + k * NTOT + n0 + nq * 4);
      ushort* base = xb + kb * 512 + (kb & 1) * 4 + j;
      base[(nq * 4 + 0) * 8] = f2hs(xv.x);
      base[(nq * 4 + 1) * 8] = f2hs(xv.y);
      base[(nq * 4 + 2) * 8] = f2hs(xv.z);
      base[(nq * 4 + 3) * 8] = f2hs(xv.w);
    }
  }
  __syncthreads();

  const int lane = tid & 63;
  const int wv   = tid >> 6;        // wave = n-subtile (16 n)
  const int ln15 = lane & 15;
  const int lq   = lane >> 4;
  const int nloc = wv * 16 + ln15;

  f32x4 acc[4];
#pragma unroll
  for (int i = 0; i < 4; ++i) acc[i] = (f32x4){0.f, 0.f, 0.f, 0.f};

#pragma unroll
  for (int kk = 0; kk < 4; ++kk) {
    const int kb = kk * 4 + lq;
    f16x4 b = *(const f16x4*)(xb + kb * 512 + nloc * 8 + (kb & 1) * 4);
#pragma unroll
    for (int mt = 0; mt < 4; ++mt) {
      f16x4 a = *(const f16x4*)(wt + (mt * 16 + ln15) * 72 + kk * 16 + lq * 4);
      acc[mt] = __builtin_amdgcn_mfma_f32_16x16x16f16(a, b, acc[mt], 0, 0, 0);
    }
  }
  // epilogue: D col=ln15=n, rows lq*4+r = ch-in-cluster -> 8B chunk per lane,
  // wave covers 512B contiguous per tile
  const int n = n0 + nloc;
#pragma unroll
  for (int mt = 0; mt < 4; ++mt) {
    const int cl = oct * 4 + mt;
    ushort4 o;
    o.x = f2hs(acc[mt][0]);
    o.y = f2hs(acc[mt][1]);
    o.z = f2hs(acc[mt][2]);
    o.w = f2hs(acc[mt][3]);
    *(ushort4*)(qkvT + ((size_t)cl * NTOT + n) * 16 + lq * 4) = o;
  }
}

// ---------------- K2: grouped 3x3x3 conv, block-diag implicit GEMM on MFMA
// Tile 4t x 8h x 16w per cluster (16 ch). Halo [6][10][18][16ch] f16, ch-rotated
// by (W>>2)&3 (bank spread). A-table compressed to diagonal blocks (3456B).
__global__ __launch_bounds__(256, 4) void k_dwconv(const ushort* __restrict__ qkvT,
                                                   const float* __restrict__ dww,
                                                   bf16* __restrict__ out) {
  const int cl = blockIdx.x;        // 0..47
  const int s  = blockIdx.y;        // 0..127
  const int wsel = s & 3, hsel = (s >> 2) & 7, tsel = s >> 5;
  const int t0 = tsel * 4, h0 = hsel * 8, w0 = wsel * 16;
  __shared__ __align__(16) ushort xh[6 * 10 * 18 * 16];  // 34560 B
  __shared__ __align__(16) ushort at[27 * 64];           //  3456 B [tap][p16][ic4]
  const int tid = threadIdx.x;

  // ---- A-table: only diagonal 4x4 blocks. p = (g'<<2)|oc
  for (int idx = tid; idx < 27 * 64; idx += 256) {
    int tap = idx >> 6;
    int p   = (idx >> 2) & 15;
    int ic  = idx & 3;
    at[idx] = f2hs(dww[(cl * 4 + (p >> 2)) * 432 + ((p & 3) * 4 + ic) * 27 + tap]);
  }
  // ---- halo staging: 1080 chunks of 16ch (32B), coalesced, rotated store
  const ushort* cb = qkvT + (size_t)cl * (NTOT * 16);
  for (int ci = tid; ci < 1080; ci += 256) {
    int W = ci % 18;
    int r = ci / 18;
    int H = r % 10;
    int T = r / 10;
    int Tg = t0 - 1 + T, Hg = h0 - 1 + H, Wg = w0 - 1 + W;
    uint4 d0 = {0, 0, 0, 0}, d1 = {0, 0, 0, 0};
    if ((unsigned)Tg < 16u && (unsigned)Hg < 64u && (unsigned)Wg < 64u) {
      const uint4* src = (const uint4*)(cb + (size_t)(Tg * 4096 + Hg * 64 + Wg) * 16);
      d0 = src[0];
      d1 = src[1];
    }
    const int rot = (W >> 2) & 3;
    uint2* dst = (uint2*)(xh + ci * 16);
    uint2 u0 = {d0.x, d0.y}, u1 = {d0.z, d0.w}, u2 = {d1.x, d1.y}, u3 = {d1.z, d1.w};
    dst[(0 + rot) & 3] = u0;
    dst[(1 + rot) & 3] = u1;
    dst[(2 + rot) & 3] = u2;
    dst[(3 + rot) & 3] = u3;
  }
  __syncthreads();

  const int lane = tid & 63;
  const int wv   = tid >> 6;        // wave id = t-offset 0..3
  const int ln15 = lane & 15;
  const int lq   = lane >> 4;       // 4-ch block
  const bool diag = (lq == (ln15 >> 2));
  // per-lane rotated read offsets for dwp = 0,1,2 (ushort units)
  const ushort* bp[3];
#pragma unroll
  for (int dwp = 0; dwp < 3; ++dwp) {
    const int Wl = ln15 + dwp;
    const int slot = (lq + (Wl >> 2)) & 3;
    bp[dwp] = xh + wv * 2880 + Wl * 16 + slot * 4;
  }
  const f16x4 z4 = {};

  f32x4 acc[8];
#pragma unroll
  for (int i = 0; i < 8; ++i) acc[i] = (f32x4){0.f, 0.f, 0.f, 0.f};

#pragma unroll
  for (int dt = 0; dt < 3; ++dt) {
#pragma unroll
    for (int dh = 0; dh < 3; ++dh) {
#pragma unroll
      for (int dwp = 0; dwp < 3; ++dwp) {
        const int tap = (dt * 3 + dh) * 3 + dwp;
        f16x4 a = *(const f16x4*)(at + tap * 64 + ln15 * 4);
        if (!diag) a = z4;
#pragma unroll
        for (int hi = 0; hi < 8; ++hi) {
          f16x4 b = *(const f16x4*)(bp[dwp] + (dt * 10 + dh + hi) * 288);
          acc[hi] = __builtin_amdgcn_mfma_f32_16x16x16f16(a, b, acc[hi], 0, 0, 0);
        }
      }
    }
  }
  // ---- epilogue: D row=(lq*4+r)=ch, col=ln15=w
  const int chbase = cl * 16 + lq * 4;
#pragma unroll
  for (int hi = 0; hi < 8; ++hi) {
    const int n = (t0 + wv) * 4096 + (h0 + hi) * 64 + w0 + ln15;
#pragma unroll
    for (int r = 0; r < 4; ++r)
      out[(size_t)(chbase + r) * NTOT + n] = __float2bfloat16(acc[hi][r]);
  }
}

// ---------------- K3: partial gram S[c][d] = sum_n q[c][n]k[d][n], plus sum q^2, k^2
__global__ __launch_bounds__(256) void k_attn_part(const bf16* __restrict__ dwout,
                                                   float* __restrict__ pS,
                                                   float* __restrict__ pQ,
                                                   float* __restrict__ pK) {
  const int head = blockIdx.y;
  const int chunk = blockIdx.x;   // 0..127, each 512 n
  const int tid = threadIdx.x;
  const ushort* qb = (const ushort*)dwout + (head * 64) * (size_t)NTOT;
  const ushort* kb = (const ushort*)dwout + (256 + head * 64) * (size_t)NTOT;
  __shared__ float lq[64][68];   // 17.4 KB
  __shared__ float lk[64][68];
  const int ci = tid & 15, di = tid >> 4;
  float acc[4][4] = {};
  float qq = 0.f, kk = 0.f;
  for (int s = 0; s < 8; ++s) {
    const int nb = chunk * 512 + s * 64;
    __syncthreads();
#pragma unroll
    for (int i = 0; i < 2; ++i) {
      int f = tid + i * 256;      // 0..511
      int c = f >> 3, n8 = f & 7;
      uint4 qv = *(const uint4*)(qb + c * NTOT + nb + n8 * 8);
      uint4 kv = *(const uint4*)(kb + c * NTOT + nb + n8 * 8);
      int r = n8 * 8;
      lq[r + 0][c] = lo2f(qv.x); lq[r + 1][c] = hi2f(qv.x);
      lq[r + 2][c] = lo2f(qv.y); lq[r + 3][c] = hi2f(qv.y);
      lq[r + 4][c] = lo2f(qv.z); lq[r + 5][c] = hi2f(qv.z);
      lq[r + 6][c] = lo2f(qv.w); lq[r + 7][c] = hi2f(qv.w);
      lk[r + 0][c] = lo2f(kv.x); lk[r + 1][c] = hi2f(kv.x);
      lk[r + 2][c] = lo2f(kv.y); lk[r + 3][c] = hi2f(kv.y);
      lk[r + 4][c] = lo2f(kv.z); lk[r + 5][c] = hi2f(kv.z);
      lk[r + 6][c] = lo2f(kv.w); lk[r + 7][c] = hi2f(kv.w);
    }
    __syncthreads();
#pragma unroll 4
    for (int j = 0; j < 64; ++j) {
      float4 q4 = *(const float4*)&lq[j][ci * 4];
      float4 k4 = *(const float4*)&lk[j][di * 4];
      float qa[4] = {q4.x, q4.y, q4.z, q4.w};
      float ka[4] = {k4.x, k4.y, k4.z, k4.w};
#pragma unroll
      for (int a = 0; a < 4; ++a)
#pragma unroll
        for (int b = 0; b < 4; ++b) acc[a][b] = fmaf(qa[a], ka[b], acc[a][b]);
    }
    if (tid < 64) {
#pragma unroll 4
      for (int j = 0; j < 64; ++j) { float v = lq[j][tid]; qq = fmaf(v, v, qq); }
    } else if (tid < 128) {
#pragma unroll 4
      for (int j = 0; j < 64; ++j) { float v = lk[j][tid - 64]; kk = fmaf(v, v, kk); }
    }
  }
  float* ps = pS + (head * 128 + chunk) * 4096;
#pragma unroll
  for (int a = 0; a < 4; ++a) {
    float4 v4 = make_float4(acc[a][0], acc[a][1], acc[a][2], acc[a][3]);
    *(float4*)(ps + (ci * 4 + a) * 64 + di * 4) = v4;
  }
  if (tid < 64) pQ[(head * 128 + chunk) * 64 + tid] = qq;
  else if (tid < 128) pK[(head * 128 + chunk) * 64 + (tid - 64)] = kk;
}

// ---------------- K4a: reduce partials, normalize, temperature, softmax -> A[h][c][d]
__global__ __launch_bounds__(256) void k_softmax(const float* __restrict__ pS,
                                                 const float* __restrict__ pQ,
                                                 const float* __restrict__ pK,
                                                 const float* __restrict__ temp,
                                                 float* __restrict__ A) {
  const int head = blockIdx.x;
  const int tid = threadIdx.x;
  __shared__ float rq[64], rk[64];
  if (tid < 64) {
    float s = 0.f;
    for (int ch = 0; ch < 128; ++ch) s += pQ[(head * 128 + ch) * 64 + tid];
    rq[tid] = 1.f / fmaxf(sqrtf(s), 1e-12f);
  } else if (tid < 128) {
    float s = 0.f;
    for (int ch = 0; ch < 128; ++ch) s += pK[(head * 128 + ch) * 64 + (tid - 64)];
    rk[tid - 64] = 1.f / fmaxf(sqrtf(s), 1e-12f);
  }
  __syncthreads();
  const int c = tid >> 2, r = tid & 3;
  float4 a0 = {0,0,0,0}, a1 = {0,0,0,0}, a2 = {0,0,0,0}, a3 = {0,0,0,0};
  const float* base = pS + head * 128 * 4096 + c * 64 + r * 16;
  for (int ch = 0; ch < 128; ++ch) {
    const float* p = base + ch * 4096;
    float4 b0 = *(const float4*)(p + 0);
    float4 b1 = *(const float4*)(p + 4);
    float4 b2 = *(const float4*)(p + 8);
    float4 b3 = *(const float4*)(p + 12);
    a0.x += b0.x; a0.y += b0.y; a0.z += b0.z; a0.w += b0.w;
    a1.x += b1.x; a1.y += b1.y; a1.z += b1.z; a1.w += b1.w;
    a2.x += b2.x; a2.y += b2.y; a2.z += b2.z; a2.w += b2.w;
    a3.x += b3.x; a3.y += b3.y; a3.z += b3.z; a3.w += b3.w;
  }
  float v[16] = {a0.x, a0.y, a0.z, a0.w, a1.x, a1.y, a1.z, a1.w,
                 a2.x, a2.y, a2.z, a2.w, a3.x, a3.y, a3.z, a3.w};
  const float tmp = temp[head];
  const float rqc = rq[c];
#pragma unroll
  for (int dd = 0; dd < 16; ++dd) v[dd] = v[dd] * rqc * rk[r * 16 + dd] * tmp;
  float m = v[0];
#pragma unroll
  for (int dd = 1; dd < 16; ++dd) m = fmaxf(m, v[dd]);
  m = fmaxf(m, __shfl_xor(m, 1));
  m = fmaxf(m, __shfl_xor(m, 2));
  float s = 0.f;
#pragma unroll
  for (int dd = 0; dd < 16; ++dd) { v[dd] = expf(v[dd] - m); s += v[dd]; }
  s += __shfl_xor(s, 1);
  s += __shfl_xor(s, 2);
  const float inv = 1.f / s;
  float* ao = A + head * 4096 + c * 64 + r * 16;
#pragma unroll
  for (int q4 = 0; q4 < 4; ++q4) {
    float4 o = make_float4(v[q4*4+0]*inv, v[q4*4+1]*inv, v[q4*4+2]*inv, v[q4*4+3]*inv);
    *(float4*)(ao + q4 * 4) = o;
  }
}

// ---------------- K4b: fold proj into attn:  Mt[h*64+d][oc] = sum_c pw[oc][h*64+c]*A[h][c][d]
__global__ __launch_bounds__(64) void k_mt(const float* __restrict__ pw,
                                           const float* __restrict__ A,
                                           float* __restrict__ Mt) {
  const int hd = blockIdx.x;   // 0..255
  const int h = hd >> 6, d = hd & 63;
  const int oc = threadIdx.x;  // 0..63
  float s = 0.f;
  for (int c = 0; c < 64; ++c)
    s = fmaf(pw[oc * 256 + h * 64 + c], A[(h * 64 + c) * 64 + d], s);
  Mt[hd * 64 + oc] = s;
}

// ---------------- K5: y[oc][n] = sum_hd Mt[hd][oc] * v[hd][n]  (PV + proj fused)
__global__ __launch_bounds__(256) void k_pv(const bf16* __restrict__ dwout,
                                            const float* __restrict__ Mt,
                                            float* __restrict__ y) {
  const int n0 = blockIdx.x * 64;
  const ushort* vb = (const ushort*)dwout + 512 * (size_t)NTOT;
  __shared__ float lv[256][64];   // 64 KB
  const int tid = threadIdx.x;
#pragma unroll
  for (int i = 0; i < 8; ++i) {
    int f = tid + i * 256;        // 0..2047
    int hd = f >> 3, n8 = f & 7;
    uint4 v = *(const uint4*)(vb + hd * NTOT + n0 + n8 * 8);
    float4 a = make_float4(lo2f(v.x), hi2f(v.x), lo2f(v.y), hi2f(v.y));
    float4 b = make_float4(lo2f(v.z), hi2f(v.z), lo2f(v.w), hi2f(v.w));
    *(float4*)&lv[hd][n8 * 8]     = a;
    *(float4*)&lv[hd][n8 * 8 + 4] = b;
  }
  __syncthreads();
  const int oci = tid >> 4, ni = tid & 15;
  float acc[4][4] = {};
#pragma unroll 4
  for (int k = 0; k < 256; ++k) {
    float4 mv = *(const float4*)(Mt + k * 64 + oci * 4);
    float4 vv = *(const float4*)&lv[k][ni * 4];
    float ma[4] = {mv.x, mv.y, mv.z, mv.w};
    float va[4] = {vv.x, vv.y, vv.z, vv.w};
#pragma unroll
    for (int a = 0; a < 4; ++a)
#pragma unroll
      for (int b = 0; b < 4; ++b) acc[a][b] = fmaf(ma[a], va[b], acc[a][b]);
  }
#pragma unroll
  for (int a = 0; a < 4; ++a) {
    float4 o = make_float4(acc[a][0], acc[a][1], acc[a][2], acc[a][3]);
    *(float4*)(y + (oci * 4 + a) * NTOT + n0 + ni * 4) = o;
  }
}

extern "C" void kernel_launch(void* const* d_in, const int* in_sizes, int n_in,
                              void* d_out, int out_size, void* d_ws, size_t ws_size,
                              hipStream_t stream) {
  const float* x      = (const float*)d_in[0];
  const float* qkv_w  = (const float*)d_in[1];
  const float* dw_w   = (const float*)d_in[2];
  const float* proj_w = (const float*)d_in[3];
  const float* temp   = (const float*)d_in[4];
  float* out = (float*)d_out;

  char* w8 = (char*)d_ws;
  ushort* qkvT = (ushort*)(w8);                        // [48][65536][16] f16 = 100,663,296 B
  bf16*  dwout = (bf16*)(w8 + 100663296ull);           // [768][n] bf16 = 100,663,296 B
  float* pS    = (float*)(w8 + 201326592ull);          // 4*128*4096 f32 = 8,388,608 B
  float* pQ    = (float*)(w8 + 209715200ull);          // 32768 f32
  float* pK    = (float*)(w8 + 209846272ull);          // 32768 f32
  float* A     = (float*)(w8 + 209977344ull);          // 16384 f32
  float* Mt    = (float*)(w8 + 210042880ull);          // 16384 f32
  // total 210,108,416 B

  k_qkv<<<dim3(1024, 12), 256, 0, stream>>>(x, qkv_w, qkvT);
  k_dwconv<<<dim3(48, 128), 256, 0, stream>>>(qkvT, dw_w, dwout);
  k_attn_part<<<dim3(128, 4), 256, 0, stream>>>(dwout, pS, pQ, pK);
  k_softmax<<<4, 256, 0, stream>>>(pS, pQ, pK, temp, A);
  k_mt<<<256, 64, 0, stream>>>(proj_w, A, Mt);
  k_pv<<<1024, 256, 0, stream>>>(dwout, Mt, out);
}

// Round 13
// 202.767 us; speedup vs baseline: 2.0470x; 1.2001x over previous
//
#include <hip/hip_runtime.h>
#include <hip/hip_bf16.h>
#include <hip/hip_fp16.h>

#define NTOT 65536   // T*H*W

typedef __hip_bfloat16 bf16;
typedef _Float16 f16;
typedef f16 f16x4 __attribute__((ext_vector_type(4)));
typedef f16 f16x8 __attribute__((ext_vector_type(8)));
typedef float f32x4 __attribute__((ext_vector_type(4)));
typedef _Float16 h2f16 __attribute__((ext_vector_type(2)));

__device__ __forceinline__ ushort f2hs(float f) {
  __half h = __float2half(f);
  return __half_as_ushort(h);
}
__device__ __forceinline__ float fdot2(unsigned a, unsigned b, float c) {
  return __builtin_amdgcn_fdot2(__builtin_bit_cast(h2f16, a),
                                __builtin_bit_cast(h2f16, b), c, false);
}
__device__ __forceinline__ f16x8 cmb(f16x4 a, f16x4 b) {
  f16x8 r;
#pragma unroll
  for (int j = 0; j < 4; ++j) { r[j] = a[j]; r[j + 4] = b[j]; }
  return r;
}

// ---------------- K1: 1x1x1 conv as MFMA GEMM; qkvT[cluster][n][16ch] f16
__global__ __launch_bounds__(256) void k_qkv(const float* __restrict__ x,
                                             const float* __restrict__ w,
                                             ushort* __restrict__ qkvT) {
  const int n0  = blockIdx.x * 64;
  const int oct = blockIdx.y;           // 0..11
  __shared__ __align__(16) ushort wt[64 * 72];     // 9216 B
  __shared__ __align__(16) ushort xb[16 * 64 * 8]; // 16384 B
  const int tid = threadIdx.x;
  const float4* w4 = (const float4*)w;
#pragma unroll
  for (int i = 0; i < 4; ++i) {
    const int idx = tid + i * 256;      // 0..1023
    {
      const int oc = idx >> 4, kq = idx & 15;
      float4 wv = w4[(oct * 64 + oc) * 16 + kq];
      ushort4 o;
      o.x = f2hs(wv.x); o.y = f2hs(wv.y); o.z = f2hs(wv.z); o.w = f2hs(wv.w);
      *(ushort4*)(wt + oc * 72 + kq * 4) = o;
    }
    {
      const int k = idx >> 4, nq = idx & 15;
      const int kb = k >> 2, j = k & 3;
      float4 xv = *(const float4*)(x + k * NTOT + n0 + nq * 4);
      ushort* base = xb + kb * 512 + (kb & 1) * 4 + j;
      base[(nq * 4 + 0) * 8] = f2hs(xv.x);
      base[(nq * 4 + 1) * 8] = f2hs(xv.y);
      base[(nq * 4 + 2) * 8] = f2hs(xv.z);
      base[(nq * 4 + 3) * 8] = f2hs(xv.w);
    }
  }
  __syncthreads();

  const int lane = tid & 63;
  const int wv   = tid >> 6;
  const int ln15 = lane & 15;
  const int lq   = lane >> 4;
  const int nloc = wv * 16 + ln15;

  f32x4 acc[4];
#pragma unroll
  for (int i = 0; i < 4; ++i) acc[i] = (f32x4){0.f, 0.f, 0.f, 0.f};

#pragma unroll
  for (int kk = 0; kk < 4; ++kk) {
    const int kb = kk * 4 + lq;
    f16x4 b = *(const f16x4*)(xb + kb * 512 + nloc * 8 + (kb & 1) * 4);
#pragma unroll
    for (int mt = 0; mt < 4; ++mt) {
      f16x4 a = *(const f16x4*)(wt + (mt * 16 + ln15) * 72 + kk * 16 + lq * 4);
      acc[mt] = __builtin_amdgcn_mfma_f32_16x16x16f16(a, b, acc[mt], 0, 0, 0);
    }
  }
  const int n = n0 + nloc;
#pragma unroll
  for (int mt = 0; mt < 4; ++mt) {
    const int cl = oct * 4 + mt;
    ushort4 o;
    o.x = f2hs(acc[mt][0]);
    o.y = f2hs(acc[mt][1]);
    o.z = f2hs(acc[mt][2]);
    o.w = f2hs(acc[mt][3]);
    *(ushort4*)(qkvT + ((size_t)cl * NTOT + n) * 16 + lq * 4) = o;
  }
}

// ---------------- K2: grouped 3x3x3 conv, block-diag implicit GEMM, K=32 tap-paired
__global__ __launch_bounds__(256, 4) void k_dwconv(const ushort* __restrict__ qkvT,
                                                   const float* __restrict__ dww,
                                                   ushort* __restrict__ out) {
  const int cl = blockIdx.x;        // 0..47
  const int s  = blockIdx.y;        // 0..127
  const int wsel = s & 3, hsel = (s >> 2) & 7, tsel = s >> 5;
  const int t0 = tsel * 4, h0 = hsel * 8, w0 = wsel * 16;
  __shared__ __align__(16) ushort xh[6 * 10 * 18 * 16];  // 34560 B
  __shared__ __align__(16) ushort at[27 * 64];           //  3456 B [tap][p16][ic4]
  const int tid = threadIdx.x;

  for (int idx = tid; idx < 27 * 64; idx += 256) {
    int tap = idx >> 6;
    int p   = (idx >> 2) & 15;
    int ic  = idx & 3;
    at[idx] = f2hs(dww[(cl * 4 + (p >> 2)) * 432 + ((p & 3) * 4 + ic) * 27 + tap]);
  }
  const ushort* cb = qkvT + (size_t)cl * (NTOT * 16);
  for (int ci = tid; ci < 1080; ci += 256) {
    int W = ci % 18;
    int r = ci / 18;
    int H = r % 10;
    int T = r / 10;
    int Tg = t0 - 1 + T, Hg = h0 - 1 + H, Wg = w0 - 1 + W;
    uint4 d0 = {0, 0, 0, 0}, d1 = {0, 0, 0, 0};
    if ((unsigned)Tg < 16u && (unsigned)Hg < 64u && (unsigned)Wg < 64u) {
      const uint4* src = (const uint4*)(cb + (size_t)(Tg * 4096 + Hg * 64 + Wg) * 16);
      d0 = src[0];
      d1 = src[1];
    }
    const int rot = (W >> 2) & 3;
    uint2* dst = (uint2*)(xh + ci * 16);
    uint2 u0 = {d0.x, d0.y}, u1 = {d0.z, d0.w}, u2 = {d1.x, d1.y}, u3 = {d1.z, d1.w};
    dst[(0 + rot) & 3] = u0;
    dst[(1 + rot) & 3] = u1;
    dst[(2 + rot) & 3] = u2;
    dst[(3 + rot) & 3] = u3;
  }
  __syncthreads();

  const int lane = tid & 63;
  const int wv   = tid >> 6;        // t-offset 0..3
  const int ln15 = lane & 15;
  const int lq   = lane >> 4;
  const bool diag = (lq == (ln15 >> 2));
  const ushort* bp[3];
#pragma unroll
  for (int dwp = 0; dwp < 3; ++dwp) {
    const int Wl = ln15 + dwp;
    const int slot = (lq + (Wl >> 2)) & 3;
    bp[dwp] = xh + wv * 2880 + Wl * 16 + slot * 4;
  }
  const f16x4 z4 = {};
  const f16x8 z8 = {};

  f32x4 acc[8];
#pragma unroll
  for (int i = 0; i < 8; ++i) acc[i] = (f32x4){0.f, 0.f, 0.f, 0.f};

#pragma unroll
  for (int p = 0; p < 14; ++p) {
    const int ta = 2 * p;
    const int tb = (2 * p + 1 < 27) ? 2 * p + 1 : 26;
    const bool pad = (2 * p + 1 >= 27);
    f16x4 a0 = *(const f16x4*)(at + ta * 64 + ln15 * 4);
    f16x4 a1 = pad ? z4 : *(const f16x4*)(at + tb * 64 + ln15 * 4);
    f16x8 a = cmb(a0, a1);
    if (!diag) a = z8;
    const int dta = ta / 9, dha = (ta % 9) / 3, dwa = ta % 3;
    const int dtb = tb / 9, dhb = (tb % 9) / 3, dwb = tb % 3;
#pragma unroll
    for (int hi = 0; hi < 8; ++hi) {
      f16x4 b0 = *(const f16x4*)(bp[dwa] + (dta * 10 + dha + hi) * 288);
      f16x4 b1 = *(const f16x4*)(bp[dwb] + (dtb * 10 + dhb + hi) * 288);
      f16x8 b = cmb(b0, b1);
      acc[hi] = __builtin_amdgcn_mfma_f32_16x16x32_f16(a, b, acc[hi], 0, 0, 0);
    }
  }
  const int chbase = cl * 16 + lq * 4;
#pragma unroll
  for (int hi = 0; hi < 8; ++hi) {
    const int n = (t0 + wv) * 4096 + (h0 + hi) * 64 + w0 + ln15;
#pragma unroll
    for (int r = 0; r < 4; ++r)
      out[(size_t)(chbase + r) * NTOT + n] = f2hs(acc[hi][r]);
  }
}

// ---------------- K3: gram via MFMA. S[c][d] = sum_n q[c][n]k[d][n]; + sum q^2,k^2
__global__ __launch_bounds__(256) void k_attn_part(const ushort* __restrict__ dwout,
                                                   float* __restrict__ pS,
                                                   float* __restrict__ pQ,
                                                   float* __restrict__ pK) {
  const int head = blockIdx.y;
  const int chunk = blockIdx.x;   // 0..127, each 512 n
  const int tid = threadIdx.x;
  const ushort* qb = dwout + (size_t)(head * 64) * NTOT;
  const ushort* kb = dwout + (size_t)(256 + head * 64) * NTOT;
  __shared__ __align__(16) ushort lsq[64][76];   // 9728 B, row 152B
  __shared__ __align__(16) ushort lsk[64][76];
  const int lane = tid & 63, wv = tid >> 6;
  const int ln15 = lane & 15, lqd = lane >> 4;
  const int c0 = wv * 16;
  const int sch = tid >> 2, spart = tid & 3;
  f32x4 acc[4];
#pragma unroll
  for (int i = 0; i < 4; ++i) acc[i] = (f32x4){0.f, 0.f, 0.f, 0.f};
  float qq = 0.f, kk = 0.f;

  for (int ph = 0; ph < 8; ++ph) {
    const int nb = chunk * 512 + ph * 64;
    __syncthreads();
#pragma unroll
    for (int i = 0; i < 2; ++i) {
      const int id = tid + i * 256;   // 0..511
      const int ch = id >> 3, n8 = id & 7;
      uint4 qv = *(const uint4*)(qb + (size_t)ch * NTOT + nb + n8 * 8);
      uint4 kv = *(const uint4*)(kb + (size_t)ch * NTOT + nb + n8 * 8);
      *(uint2*)&lsq[ch][n8 * 8]     = (uint2){qv.x, qv.y};
      *(uint2*)&lsq[ch][n8 * 8 + 4] = (uint2){qv.z, qv.w};
      *(uint2*)&lsk[ch][n8 * 8]     = (uint2){kv.x, kv.y};
      *(uint2*)&lsk[ch][n8 * 8 + 4] = (uint2){kv.z, kv.w};
    }
    __syncthreads();
#pragma unroll
    for (int ks = 0; ks < 2; ++ks) {
      f16x4 a0 = *(const f16x4*)&lsq[c0 + ln15][ks * 32 + lqd * 4];
      f16x4 a1 = *(const f16x4*)&lsq[c0 + ln15][ks * 32 + lqd * 4 + 16];
      f16x8 a = cmb(a0, a1);
#pragma unroll
      for (int d = 0; d < 4; ++d) {
        f16x4 b0 = *(const f16x4*)&lsk[d * 16 + ln15][ks * 32 + lqd * 4];
        f16x4 b1 = *(const f16x4*)&lsk[d * 16 + ln15][ks * 32 + lqd * 4 + 16];
        f16x8 b = cmb(b0, b1);
        acc[d] = __builtin_amdgcn_mfma_f32_16x16x32_f16(a, b, acc[d], 0, 0, 0);
      }
    }
    // qq/kk partials: thread (sch, spart) covers 16 n
#pragma unroll
    for (int j4 = 0; j4 < 4; ++j4) {
      uint2 qv = *(const uint2*)&lsq[sch][spart * 16 + j4 * 4];
      uint2 kv = *(const uint2*)&lsk[sch][spart * 16 + j4 * 4];
      qq = fdot2(qv.x, qv.x, qq); qq = fdot2(qv.y, qv.y, qq);
      kk = fdot2(kv.x, kv.x, kk); kk = fdot2(kv.y, kv.y, kk);
    }
  }
  qq += __shfl_xor(qq, 1); qq += __shfl_xor(qq, 2);
  kk += __shfl_xor(kk, 1); kk += __shfl_xor(kk, 2);
  if (spart == 0) {
    pQ[(head * 128 + chunk) * 64 + sch] = qq;
    pK[(head * 128 + chunk) * 64 + sch] = kk;
  }
  float* ps = pS + (size_t)(head * 128 + chunk) * 4096;
#pragma unroll
  for (int d = 0; d < 4; ++d)
#pragma unroll
    for (int r = 0; r < 4; ++r)
      ps[(c0 + lqd * 4 + r) * 64 + d * 16 + ln15] = acc[d][r];
}

// ---------------- K4a: reduce partials, normalize, temperature, softmax -> A[h][c][d]
__global__ __launch_bounds__(256) void k_softmax(const float* __restrict__ pS,
                                                 const float* __restrict__ pQ,
                                                 const float* __restrict__ pK,
                                                 const float* __restrict__ temp,
                                                 float* __restrict__ A) {
  const int head = blockIdx.x;
  const int tid = threadIdx.x;
  __shared__ float rq[64], rk[64];
  if (tid < 64) {
    float s = 0.f;
    for (int ch = 0; ch < 128; ++ch) s += pQ[(head * 128 + ch) * 64 + tid];
    rq[tid] = 1.f / fmaxf(sqrtf(s), 1e-12f);
  } else if (tid < 128) {
    float s = 0.f;
    for (int ch = 0; ch < 128; ++ch) s += pK[(head * 128 + ch) * 64 + (tid - 64)];
    rk[tid - 64] = 1.f / fmaxf(sqrtf(s), 1e-12f);
  }
  __syncthreads();
  const int c = tid >> 2, r = tid & 3;
  float4 a0 = {0,0,0,0}, a1 = {0,0,0,0}, a2 = {0,0,0,0}, a3 = {0,0,0,0};
  const float* base = pS + head * 128 * 4096 + c * 64 + r * 16;
  for (int ch = 0; ch < 128; ++ch) {
    const float* p = base + ch * 4096;
    float4 b0 = *(const float4*)(p + 0);
    float4 b1 = *(const float4*)(p + 4);
    float4 b2 = *(const float4*)(p + 8);
    float4 b3 = *(const float4*)(p + 12);
    a0.x += b0.x; a0.y += b0.y; a0.z += b0.z; a0.w += b0.w;
    a1.x += b1.x; a1.y += b1.y; a1.z += b1.z; a1.w += b1.w;
    a2.x += b2.x; a2.y += b2.y; a2.z += b2.z; a2.w += b2.w;
    a3.x += b3.x; a3.y += b3.y; a3.z += b3.z; a3.w += b3.w;
  }
  float v[16] = {a0.x, a0.y, a0.z, a0.w, a1.x, a1.y, a1.z, a1.w,
                 a2.x, a2.y, a2.z, a2.w, a3.x, a3.y, a3.z, a3.w};
  const float tmp = temp[head];
  const float rqc = rq[c];
#pragma unroll
  for (int dd = 0; dd < 16; ++dd) v[dd] = v[dd] * rqc * rk[r * 16 + dd] * tmp;
  float m = v[0];
#pragma unroll
  for (int dd = 1; dd < 16; ++dd) m = fmaxf(m, v[dd]);
  m = fmaxf(m, __shfl_xor(m, 1));
  m = fmaxf(m, __shfl_xor(m, 2));
  float s = 0.f;
#pragma unroll
  for (int dd = 0; dd < 16; ++dd) { v[dd] = expf(v[dd] - m); s += v[dd]; }
  s += __shfl_xor(s, 1);
  s += __shfl_xor(s, 2);
  const float inv = 1.f / s;
  float* ao = A + head * 4096 + c * 64 + r * 16;
#pragma unroll
  for (int q4 = 0; q4 < 4; ++q4) {
    float4 o = make_float4(v[q4*4+0]*inv, v[q4*4+1]*inv, v[q4*4+2]*inv, v[q4*4+3]*inv);
    *(float4*)(ao + q4 * 4) = o;
  }
}

// ---------------- K4b: MtT[oc][h*64+d] = sum_c pw[oc][h*64+c]*A[h][c][d]  (f16)
__global__ __launch_bounds__(64) void k_mt(const float* __restrict__ pw,
                                           const float* __restrict__ A,
                                           ushort* __restrict__ MtT) {
  const int hd = blockIdx.x;   // 0..255
  const int h = hd >> 6, d = hd & 63;
  const int oc = threadIdx.x;  // 0..63
  float s = 0.f;
  for (int c = 0; c < 64; ++c)
    s = fmaf(pw[oc * 256 + h * 64 + c], A[(h * 64 + c) * 64 + d], s);
  MtT[oc * 256 + hd] = f2hs(s);
}

// ---------------- K5: y[oc][n] = sum_hd MtT[oc][hd] * v[hd][n]  via MFMA
__global__ __launch_bounds__(256) void k_pv(const ushort* __restrict__ dwout,
                                            const ushort* __restrict__ MtT,
                                            float* __restrict__ y) {
  const int n0 = blockIdx.x * 64;
  const ushort* vb = dwout + 512 * (size_t)NTOT;
  __shared__ __align__(16) ushort vt[64 * 256];   // 32 KB: [n][hd] quad-rotated
  const int tid = threadIdx.x;
#pragma unroll
  for (int i = 0; i < 2; ++i) {
    const int id = tid + i * 256;    // 0..511
    const int kq = id >> 3;          // hd-quad 0..63
    const int ng = id & 7;           // n-octet
    uint4 r0 = *(const uint4*)(vb + (size_t)(kq * 4 + 0) * NTOT + n0 + ng * 8);
    uint4 r1 = *(const uint4*)(vb + (size_t)(kq * 4 + 1) * NTOT + n0 + ng * 8);
    uint4 r2 = *(const uint4*)(vb + (size_t)(kq * 4 + 2) * NTOT + n0 + ng * 8);
    uint4 r3 = *(const uint4*)(vb + (size_t)(kq * 4 + 3) * NTOT + n0 + ng * 8);
    const ushort* h0 = (const ushort*)&r0;
    const ushort* h1 = (const ushort*)&r1;
    const ushort* h2 = (const ushort*)&r2;
    const ushort* h3 = (const ushort*)&r3;
#pragma unroll
    for (int j = 0; j < 8; ++j) {
      const int n = ng * 8 + j;
      unsigned lo = (unsigned)h0[j] | ((unsigned)h1[j] << 16);
      unsigned hi = (unsigned)h2[j] | ((unsigned)h3[j] << 16);
      const int slot = (kq + n + (n >> 3)) & 63;
      *(uint2*)(vt + n * 256 + slot * 4) = (uint2){lo, hi};
    }
  }
  __syncthreads();

  const int lane = tid & 63;
  const int wv   = tid >> 6;
  const int ln15 = lane & 15, lq = lane >> 4;
  const int nloc = wv * 16 + ln15;
  const int nrot = nloc + (nloc >> 3);

  f32x4 acc[4];
#pragma unroll
  for (int i = 0; i < 4; ++i) acc[i] = (f32x4){0.f, 0.f, 0.f, 0.f};

#pragma unroll
  for (int kb = 0; kb < 8; ++kb) {
    const int kq0 = kb * 8 + lq;
    const int s0 = ((kq0 + nrot) & 63) * 4;
    const int s1 = ((kq0 + 4 + nrot) & 63) * 4;
    f16x4 b0 = *(const f16x4*)(vt + nloc * 256 + s0);
    f16x4 b1 = *(const f16x4*)(vt + nloc * 256 + s1);
    f16x8 b = cmb(b0, b1);
#pragma unroll
    for (int mt = 0; mt < 4; ++mt) {
      const ushort* ap = MtT + (mt * 16 + ln15) * 256 + kb * 32 + lq * 4;
      f16x4 a0 = *(const f16x4*)(ap);
      f16x4 a1 = *(const f16x4*)(ap + 16);
      f16x8 a = cmb(a0, a1);
      acc[mt] = __builtin_amdgcn_mfma_f32_16x16x32_f16(a, b, acc[mt], 0, 0, 0);
    }
  }
  const int n = n0 + nloc;
#pragma unroll
  for (int mt = 0; mt < 4; ++mt) {
    const int oc = mt * 16 + lq * 4;
#pragma unroll
    for (int r = 0; r < 4; ++r)
      y[(size_t)(oc + r) * NTOT + n] = acc[mt][r];
  }
}

extern "C" void kernel_launch(void* const* d_in, const int* in_sizes, int n_in,
                              void* d_out, int out_size, void* d_ws, size_t ws_size,
                              hipStream_t stream) {
  const float* x      = (const float*)d_in[0];
  const float* qkv_w  = (const float*)d_in[1];
  const float* dw_w   = (const float*)d_in[2];
  const float* proj_w = (const float*)d_in[3];
  const float* temp   = (const float*)d_in[4];
  float* out = (float*)d_out;

  char* w8 = (char*)d_ws;
  ushort* qkvT = (ushort*)(w8);                        // [48][65536][16] f16 = 100,663,296 B
  ushort* dwout = (ushort*)(w8 + 100663296ull);        // [768][n] f16 = 100,663,296 B
  float* pS    = (float*)(w8 + 201326592ull);          // 4*128*4096 f32 = 8,388,608 B
  float* pQ    = (float*)(w8 + 209715200ull);          // 32768 f32
  float* pK    = (float*)(w8 + 209846272ull);          // 32768 f32
  float* A     = (float*)(w8 + 209977344ull);          // 16384 f32
  ushort* MtT  = (ushort*)(w8 + 210042880ull);         // 64*256 f16 = 32768 B
  // total ~210 MB

  k_qkv<<<dim3(1024, 12), 256, 0, stream>>>(x, qkv_w, qkvT);
  k_dwconv<<<dim3(48, 128), 256, 0, stream>>>(qkvT, dw_w, dwout);
  k_attn_part<<<dim3(128, 4), 256, 0, stream>>>(dwout, pS, pQ, pK);
  k_softmax<<<4, 256, 0, stream>>>(pS, pQ, pK, temp, A);
  k_mt<<<256, 64, 0, stream>>>(proj_w, A, MtT);
  k_pv<<<1024, 256, 0, stream>>>(dwout, MtT, out);
}

// Round 14
// 199.152 us; speedup vs baseline: 2.0841x; 1.0182x over previous
//
#include <hip/hip_runtime.h>
#include <hip/hip_bf16.h>
#include <hip/hip_fp16.h>

#define NTOT 65536   // T*H*W

typedef __hip_bfloat16 bf16;
typedef _Float16 f16;
typedef f16 f16x4 __attribute__((ext_vector_type(4)));
typedef f16 f16x8 __attribute__((ext_vector_type(8)));
typedef float f32x4 __attribute__((ext_vector_type(4)));
typedef _Float16 h2f16 __attribute__((ext_vector_type(2)));

__device__ __forceinline__ ushort f2hs(float f) {
  __half h = __float2half(f);
  return __half_as_ushort(h);
}
__device__ __forceinline__ float fdot2(unsigned a, unsigned b, float c) {
  return __builtin_amdgcn_fdot2(__builtin_bit_cast(h2f16, a),
                                __builtin_bit_cast(h2f16, b), c, false);
}
__device__ __forceinline__ f16x8 cmb(f16x4 a, f16x4 b) {
  f16x8 r;
#pragma unroll
  for (int j = 0; j < 4; ++j) { r[j] = a[j]; r[j + 4] = b[j]; }
  return r;
}

// ---------------- K1: 1x1x1 conv as MFMA GEMM; qkvT[cluster][n][16ch] f16
__global__ __launch_bounds__(256) void k_qkv(const float* __restrict__ x,
                                             const float* __restrict__ w,
                                             ushort* __restrict__ qkvT) {
  const int n0  = blockIdx.x * 64;
  const int oct = blockIdx.y;           // 0..11
  __shared__ __align__(16) ushort wt[64 * 72];     // 9216 B
  __shared__ __align__(16) ushort xb[16 * 64 * 8]; // 16384 B
  const int tid = threadIdx.x;
  const float4* w4 = (const float4*)w;
#pragma unroll
  for (int i = 0; i < 4; ++i) {
    const int idx = tid + i * 256;      // 0..1023
    {
      const int oc = idx >> 4, kq = idx & 15;
      float4 wv = w4[(oct * 64 + oc) * 16 + kq];
      ushort4 o;
      o.x = f2hs(wv.x); o.y = f2hs(wv.y); o.z = f2hs(wv.z); o.w = f2hs(wv.w);
      *(ushort4*)(wt + oc * 72 + kq * 4) = o;
    }
    {
      const int k = idx >> 4, nq = idx & 15;
      const int kb = k >> 2, j = k & 3;
      float4 xv = *(const float4*)(x + k * NTOT + n0 + nq * 4);
      ushort* base = xb + kb * 512 + (kb & 1) * 4 + j;
      base[(nq * 4 + 0) * 8] = f2hs(xv.x);
      base[(nq * 4 + 1) * 8] = f2hs(xv.y);
      base[(nq * 4 + 2) * 8] = f2hs(xv.z);
      base[(nq * 4 + 3) * 8] = f2hs(xv.w);
    }
  }
  __syncthreads();

  const int lane = tid & 63;
  const int wv   = tid >> 6;
  const int ln15 = lane & 15;
  const int lq   = lane >> 4;
  const int nloc = wv * 16 + ln15;

  f32x4 acc[4];
#pragma unroll
  for (int i = 0; i < 4; ++i) acc[i] = (f32x4){0.f, 0.f, 0.f, 0.f};

#pragma unroll
  for (int kk = 0; kk < 4; ++kk) {
    const int kb = kk * 4 + lq;
    f16x4 b = *(const f16x4*)(xb + kb * 512 + nloc * 8 + (kb & 1) * 4);
#pragma unroll
    for (int mt = 0; mt < 4; ++mt) {
      f16x4 a = *(const f16x4*)(wt + (mt * 16 + ln15) * 72 + kk * 16 + lq * 4);
      acc[mt] = __builtin_amdgcn_mfma_f32_16x16x16f16(a, b, acc[mt], 0, 0, 0);
    }
  }
  const int n = n0 + nloc;
#pragma unroll
  for (int mt = 0; mt < 4; ++mt) {
    const int cl = oct * 4 + mt;
    ushort4 o;
    o.x = f2hs(acc[mt][0]);
    o.y = f2hs(acc[mt][1]);
    o.z = f2hs(acc[mt][2]);
    o.w = f2hs(acc[mt][3]);
    *(ushort4*)(qkvT + ((size_t)cl * NTOT + n) * 16 + lq * 4) = o;
  }
}

// ---------------- K2: grouped 3x3x3 conv, block-diag implicit GEMM on MFMA K=16.
// Wave covers 4t x 2h x 16w: B-planes cached in regs, reused across dt (2 MFMA/read).
__global__ __launch_bounds__(256, 4) void k_dwconv(const ushort* __restrict__ qkvT,
                                                   const float* __restrict__ dww,
                                                   ushort* __restrict__ out) {
  const int cl = blockIdx.x;        // 0..47
  const int s  = blockIdx.y;        // 0..127
  const int wsel = s & 3, hsel = (s >> 2) & 7, tsel = s >> 5;
  const int t0 = tsel * 4, h0 = hsel * 8, w0 = wsel * 16;
  __shared__ __align__(16) ushort xh[6 * 10 * 18 * 16];  // 34560 B
  __shared__ __align__(16) ushort at[27 * 64];           //  3456 B [tap][p16][ic4]
  const int tid = threadIdx.x;

  for (int idx = tid; idx < 27 * 64; idx += 256) {
    int tap = idx >> 6;
    int p   = (idx >> 2) & 15;
    int ic  = idx & 3;
    at[idx] = f2hs(dww[(cl * 4 + (p >> 2)) * 432 + ((p & 3) * 4 + ic) * 27 + tap]);
  }
  const ushort* cb = qkvT + (size_t)cl * (NTOT * 16);
  for (int ci = tid; ci < 1080; ci += 256) {
    int W = ci % 18;
    int r = ci / 18;
    int H = r % 10;
    int T = r / 10;
    int Tg = t0 - 1 + T, Hg = h0 - 1 + H, Wg = w0 - 1 + W;
    uint4 d0 = {0, 0, 0, 0}, d1 = {0, 0, 0, 0};
    if ((unsigned)Tg < 16u && (unsigned)Hg < 64u && (unsigned)Wg < 64u) {
      const uint4* src = (const uint4*)(cb + (size_t)(Tg * 4096 + Hg * 64 + Wg) * 16);
      d0 = src[0];
      d1 = src[1];
    }
    const int rot = (W >> 2) & 3;
    uint2* dst = (uint2*)(xh + ci * 16);
    uint2 u0 = {d0.x, d0.y}, u1 = {d0.z, d0.w}, u2 = {d1.x, d1.y}, u3 = {d1.z, d1.w};
    dst[(0 + rot) & 3] = u0;
    dst[(1 + rot) & 3] = u1;
    dst[(2 + rot) & 3] = u2;
    dst[(3 + rot) & 3] = u3;
  }
  __syncthreads();

  const int lane = tid & 63;
  const int wv   = tid >> 6;        // h-pair index: wave covers h = wv*2, wv*2+1
  const int hp   = wv * 2;
  const int ln15 = lane & 15;
  const int lq   = lane >> 4;
  const bool diag = (lq == (ln15 >> 2));
  const ushort* bp[3];
#pragma unroll
  for (int dwp = 0; dwp < 3; ++dwp) {
    const int Wl = ln15 + dwp;
    const int slot = (lq + (Wl >> 2)) & 3;
    bp[dwp] = xh + Wl * 16 + slot * 4;
  }
  const f16x4 z4 = {};

  f32x4 acc[4][2];   // [t][h2]
#pragma unroll
  for (int a = 0; a < 4; ++a)
#pragma unroll
    for (int b = 0; b < 2; ++b) acc[a][b] = (f32x4){0.f, 0.f, 0.f, 0.f};

#pragma unroll
  for (int dh = 0; dh < 3; ++dh) {
#pragma unroll
    for (int dwp = 0; dwp < 3; ++dwp) {
      // cache 6 t-planes x 2 h rows
      f16x4 B[6][2];
#pragma unroll
      for (int tt = 0; tt < 6; ++tt)
#pragma unroll
        for (int h2 = 0; h2 < 2; ++h2)
          B[tt][h2] = *(const f16x4*)(bp[dwp] + (tt * 10 + hp + h2 + dh) * 288);
#pragma unroll
      for (int dt = 0; dt < 3; ++dt) {
        const int tap = (dt * 3 + dh) * 3 + dwp;
        f16x4 a = *(const f16x4*)(at + tap * 64 + ln15 * 4);
        if (!diag) a = z4;
#pragma unroll
        for (int t = 0; t < 4; ++t)
#pragma unroll
          for (int h2 = 0; h2 < 2; ++h2)
            acc[t][h2] = __builtin_amdgcn_mfma_f32_16x16x16f16(a, B[t + dt][h2],
                                                               acc[t][h2], 0, 0, 0);
      }
    }
  }
  const int chbase = cl * 16 + lq * 4;
#pragma unroll
  for (int t = 0; t < 4; ++t)
#pragma unroll
    for (int h2 = 0; h2 < 2; ++h2) {
      const int n = (t0 + t) * 4096 + (h0 + hp + h2) * 64 + w0 + ln15;
#pragma unroll
      for (int r = 0; r < 4; ++r)
        out[(size_t)(chbase + r) * NTOT + n] = f2hs(acc[t][h2][r]);
    }
}

// ---------------- K3: gram via MFMA. S[c][d] = sum_n q[c][n]k[d][n]; + sum q^2,k^2
__global__ __launch_bounds__(256) void k_attn_part(const ushort* __restrict__ dwout,
                                                   float* __restrict__ pS,
                                                   float* __restrict__ pQ,
                                                   float* __restrict__ pK) {
  const int head = blockIdx.y;
  const int chunk = blockIdx.x;   // 0..127, each 512 n
  const int tid = threadIdx.x;
  const ushort* qb = dwout + (size_t)(head * 64) * NTOT;
  const ushort* kb = dwout + (size_t)(256 + head * 64) * NTOT;
  __shared__ __align__(16) ushort lsq[64][76];   // 9728 B, row 152B
  __shared__ __align__(16) ushort lsk[64][76];
  const int lane = tid & 63, wv = tid >> 6;
  const int ln15 = lane & 15, lqd = lane >> 4;
  const int c0 = wv * 16;
  const int sch = tid >> 2, spart = tid & 3;
  f32x4 acc[4];
#pragma unroll
  for (int i = 0; i < 4; ++i) acc[i] = (f32x4){0.f, 0.f, 0.f, 0.f};
  float qq = 0.f, kk = 0.f;

  for (int ph = 0; ph < 8; ++ph) {
    const int nb = chunk * 512 + ph * 64;
    __syncthreads();
#pragma unroll
    for (int i = 0; i < 2; ++i) {
      const int id = tid + i * 256;   // 0..511
      const int ch = id >> 3, n8 = id & 7;
      uint4 qv = *(const uint4*)(qb + (size_t)ch * NTOT + nb + n8 * 8);
      uint4 kv = *(const uint4*)(kb + (size_t)ch * NTOT + nb + n8 * 8);
      *(uint2*)&lsq[ch][n8 * 8]     = (uint2){qv.x, qv.y};
      *(uint2*)&lsq[ch][n8 * 8 + 4] = (uint2){qv.z, qv.w};
      *(uint2*)&lsk[ch][n8 * 8]     = (uint2){kv.x, kv.y};
      *(uint2*)&lsk[ch][n8 * 8 + 4] = (uint2){kv.z, kv.w};
    }
    __syncthreads();
#pragma unroll
    for (int ks = 0; ks < 2; ++ks) {
      f16x4 a0 = *(const f16x4*)&lsq[c0 + ln15][ks * 32 + lqd * 4];
      f16x4 a1 = *(const f16x4*)&lsq[c0 + ln15][ks * 32 + lqd * 4 + 16];
      f16x8 a = cmb(a0, a1);
#pragma unroll
      for (int d = 0; d < 4; ++d) {
        f16x4 b0 = *(const f16x4*)&lsk[d * 16 + ln15][ks * 32 + lqd * 4];
        f16x4 b1 = *(const f16x4*)&lsk[d * 16 + ln15][ks * 32 + lqd * 4 + 16];
        f16x8 b = cmb(b0, b1);
        acc[d] = __builtin_amdgcn_mfma_f32_16x16x32_f16(a, b, acc[d], 0, 0, 0);
      }
    }
#pragma unroll
    for (int j4 = 0; j4 < 4; ++j4) {
      uint2 qv = *(const uint2*)&lsq[sch][spart * 16 + j4 * 4];
      uint2 kv = *(const uint2*)&lsk[sch][spart * 16 + j4 * 4];
      qq = fdot2(qv.x, qv.x, qq); qq = fdot2(qv.y, qv.y, qq);
      kk = fdot2(kv.x, kv.x, kk); kk = fdot2(kv.y, kv.y, kk);
    }
  }
  qq += __shfl_xor(qq, 1); qq += __shfl_xor(qq, 2);
  kk += __shfl_xor(kk, 1); kk += __shfl_xor(kk, 2);
  if (spart == 0) {
    pQ[(head * 128 + chunk) * 64 + sch] = qq;
    pK[(head * 128 + chunk) * 64 + sch] = kk;
  }
  float* ps = pS + (size_t)(head * 128 + chunk) * 4096;
#pragma unroll
  for (int d = 0; d < 4; ++d)
#pragma unroll
    for (int r = 0; r < 4; ++r)
      ps[(c0 + lqd * 4 + r) * 64 + d * 16 + ln15] = acc[d][r];
}

// ---------------- K4a: reduce partials, normalize, temperature, softmax -> A[h][c][d]
__global__ __launch_bounds__(256) void k_softmax(const float* __restrict__ pS,
                                                 const float* __restrict__ pQ,
                                                 const float* __restrict__ pK,
                                                 const float* __restrict__ temp,
                                                 float* __restrict__ A) {
  const int head = blockIdx.x;
  const int tid = threadIdx.x;
  __shared__ float rq[64], rk[64];
  if (tid < 64) {
    float s = 0.f;
    for (int ch = 0; ch < 128; ++ch) s += pQ[(head * 128 + ch) * 64 + tid];
    rq[tid] = 1.f / fmaxf(sqrtf(s), 1e-12f);
  } else if (tid < 128) {
    float s = 0.f;
    for (int ch = 0; ch < 128; ++ch) s += pK[(head * 128 + ch) * 64 + (tid - 64)];
    rk[tid - 64] = 1.f / fmaxf(sqrtf(s), 1e-12f);
  }
  __syncthreads();
  const int c = tid >> 2, r = tid & 3;
  float4 a0 = {0,0,0,0}, a1 = {0,0,0,0}, a2 = {0,0,0,0}, a3 = {0,0,0,0};
  const float* base = pS + head * 128 * 4096 + c * 64 + r * 16;
  for (int ch = 0; ch < 128; ++ch) {
    const float* p = base + ch * 4096;
    float4 b0 = *(const float4*)(p + 0);
    float4 b1 = *(const float4*)(p + 4);
    float4 b2 = *(const float4*)(p + 8);
    float4 b3 = *(const float4*)(p + 12);
    a0.x += b0.x; a0.y += b0.y; a0.z += b0.z; a0.w += b0.w;
    a1.x += b1.x; a1.y += b1.y; a1.z += b1.z; a1.w += b1.w;
    a2.x += b2.x; a2.y += b2.y; a2.z += b2.z; a2.w += b2.w;
    a3.x += b3.x; a3.y += b3.y; a3.z += b3.z; a3.w += b3.w;
  }
  float v[16] = {a0.x, a0.y, a0.z, a0.w, a1.x, a1.y, a1.z, a1.w,
                 a2.x, a2.y, a2.z, a2.w, a3.x, a3.y, a3.z, a3.w};
  const float tmp = temp[head];
  const float rqc = rq[c];
#pragma unroll
  for (int dd = 0; dd < 16; ++dd) v[dd] = v[dd] * rqc * rk[r * 16 + dd] * tmp;
  float m = v[0];
#pragma unroll
  for (int dd = 1; dd < 16; ++dd) m = fmaxf(m, v[dd]);
  m = fmaxf(m, __shfl_xor(m, 1));
  m = fmaxf(m, __shfl_xor(m, 2));
  float s = 0.f;
#pragma unroll
  for (int dd = 0; dd < 16; ++dd) { v[dd] = expf(v[dd] - m); s += v[dd]; }
  s += __shfl_xor(s, 1);
  s += __shfl_xor(s, 2);
  const float inv = 1.f / s;
  float* ao = A + head * 4096 + c * 64 + r * 16;
#pragma unroll
  for (int q4 = 0; q4 < 4; ++q4) {
    float4 o = make_float4(v[q4*4+0]*inv, v[q4*4+1]*inv, v[q4*4+2]*inv, v[q4*4+3]*inv);
    *(float4*)(ao + q4 * 4) = o;
  }
}

// ---------------- K4b: MtT[oc][h*64+d] = sum_c pw[oc][h*64+c]*A[h][c][d]  (f16)
__global__ __launch_bounds__(64) void k_mt(const float* __restrict__ pw,
                                           const float* __restrict__ A,
                                           ushort* __restrict__ MtT) {
  const int hd = blockIdx.x;   // 0..255
  const int h = hd >> 6, d = hd & 63;
  const int oc = threadIdx.x;  // 0..63
  float s = 0.f;
  for (int c = 0; c < 64; ++c)
    s = fmaf(pw[oc * 256 + h * 64 + c], A[(h * 64 + c) * 64 + d], s);
  MtT[oc * 256 + hd] = f2hs(s);
}

// ---------------- K5: y[oc][n] = sum_hd MtT[oc][hd] * v[hd][n]  via MFMA
__global__ __launch_bounds__(256) void k_pv(const ushort* __restrict__ dwout,
                                            const ushort* __restrict__ MtT,
                                            float* __restrict__ y) {
  const int n0 = blockIdx.x * 64;
  const ushort* vb = dwout + 512 * (size_t)NTOT;
  __shared__ __align__(16) ushort vt[64 * 256];   // 32 KB: [n][hd] quad-rotated
  const int tid = threadIdx.x;
#pragma unroll
  for (int i = 0; i < 2; ++i) {
    const int id = tid + i * 256;    // 0..511
    const int kq = id >> 3;          // hd-quad 0..63
    const int ng = id & 7;           // n-octet
    uint4 r0 = *(const uint4*)(vb + (size_t)(kq * 4 + 0) * NTOT + n0 + ng * 8);
    uint4 r1 = *(const uint4*)(vb + (size_t)(kq * 4 + 1) * NTOT + n0 + ng * 8);
    uint4 r2 = *(const uint4*)(vb + (size_t)(kq * 4 + 2) * NTOT + n0 + ng * 8);
    uint4 r3 = *(const uint4*)(vb + (size_t)(kq * 4 + 3) * NTOT + n0 + ng * 8);
    const ushort* h0 = (const ushort*)&r0;
    const ushort* h1 = (const ushort*)&r1;
    const ushort* h2 = (const ushort*)&r2;
    const ushort* h3 = (const ushort*)&r3;
#pragma unroll
    for (int j = 0; j < 8; ++j) {
      const int n = ng * 8 + j;
      unsigned lo = (unsigned)h0[j] | ((unsigned)h1[j] << 16);
      unsigned hi = (unsigned)h2[j] | ((unsigned)h3[j] << 16);
      const int slot = (kq + n + (n >> 3)) & 63;
      *(uint2*)(vt + n * 256 + slot * 4) = (uint2){lo, hi};
    }
  }
  __syncthreads();

  const int lane = tid & 63;
  const int wv   = tid >> 6;
  const int ln15 = lane & 15, lq = lane >> 4;
  const int nloc = wv * 16 + ln15;
  const int nrot = nloc + (nloc >> 3);

  f32x4 acc[4];
#pragma unroll
  for (int i = 0; i < 4; ++i) acc[i] = (f32x4){0.f, 0.f, 0.f, 0.f};

#pragma unroll
  for (int kb = 0; kb < 8; ++kb) {
    const int kq0 = kb * 8 + lq;
    const int s0 = ((kq0 + nrot) & 63) * 4;
    const int s1 = ((kq0 + 4 + nrot) & 63) * 4;
    f16x4 b0 = *(const f16x4*)(vt + nloc * 256 + s0);
    f16x4 b1 = *(const f16x4*)(vt + nloc * 256 + s1);
    f16x8 b = cmb(b0, b1);
#pragma unroll
    for (int mt = 0; mt < 4; ++mt) {
      const ushort* ap = MtT + (mt * 16 + ln15) * 256 + kb * 32 + lq * 4;
      f16x4 a0 = *(const f16x4*)(ap);
      f16x4 a1 = *(const f16x4*)(ap + 16);
      f16x8 a = cmb(a0, a1);
      acc[mt] = __builtin_amdgcn_mfma_f32_16x16x32_f16(a, b, acc[mt], 0, 0, 0);
    }
  }
  const int n = n0 + nloc;
#pragma unroll
  for (int mt = 0; mt < 4; ++mt) {
    const int oc = mt * 16 + lq * 4;
#pragma unroll
    for (int r = 0; r < 4; ++r)
      y[(size_t)(oc + r) * NTOT + n] = acc[mt][r];
  }
}

extern "C" void kernel_launch(void* const* d_in, const int* in_sizes, int n_in,
                              void* d_out, int out_size, void* d_ws, size_t ws_size,
                              hipStream_t stream) {
  const float* x      = (const float*)d_in[0];
  const float* qkv_w  = (const float*)d_in[1];
  const float* dw_w   = (const float*)d_in[2];
  const float* proj_w = (const float*)d_in[3];
  const float* temp   = (const float*)d_in[4];
  float* out = (float*)d_out;

  char* w8 = (char*)d_ws;
  ushort* qkvT = (ushort*)(w8);                        // [48][65536][16] f16 = 100,663,296 B
  ushort* dwout = (ushort*)(w8 + 100663296ull);        // [768][n] f16 = 100,663,296 B
  float* pS    = (float*)(w8 + 201326592ull);          // 4*128*4096 f32 = 8,388,608 B
  float* pQ    = (float*)(w8 + 209715200ull);          // 32768 f32
  float* pK    = (float*)(w8 + 209846272ull);          // 32768 f32
  float* A     = (float*)(w8 + 209977344ull);          // 16384 f32
  ushort* MtT  = (ushort*)(w8 + 210042880ull);         // 64*256 f16 = 32768 B
  // total ~210 MB

  k_qkv<<<dim3(1024, 12), 256, 0, stream>>>(x, qkv_w, qkvT);
  k_dwconv<<<dim3(48, 128), 256, 0, stream>>>(qkvT, dw_w, dwout);
  k_attn_part<<<dim3(128, 4), 256, 0, stream>>>(dwout, pS, pQ, pK);
  k_softmax<<<4, 256, 0, stream>>>(pS, pQ, pK, temp, A);
  k_mt<<<256, 64, 0, stream>>>(proj_w, A, MtT);
  k_pv<<<1024, 256, 0, stream>>>(dwout, MtT, out);
}

// Round 17
// 184.695 us; speedup vs baseline: 2.2473x; 1.0783x over previous
//
#include <hip/hip_runtime.h>
#include <hip/hip_bf16.h>
#include <hip/hip_fp16.h>

#define NTOT 65536   // T*H*W

typedef __hip_bfloat16 bf16;
typedef _Float16 f16;
typedef f16 f16x4 __attribute__((ext_vector_type(4)));
typedef f16 f16x8 __attribute__((ext_vector_type(8)));
typedef float f32x4 __attribute__((ext_vector_type(4)));
typedef _Float16 h2f16 __attribute__((ext_vector_type(2)));

__device__ __forceinline__ ushort f2hs(float f) {
  __half h = __float2half(f);
  return __half_as_ushort(h);
}
__device__ __forceinline__ float fdot2(unsigned a, unsigned b, float c) {
  return __builtin_amdgcn_fdot2(__builtin_bit_cast(h2f16, a),
                                __builtin_bit_cast(h2f16, b), c, false);
}
__device__ __forceinline__ f16x8 cmb(f16x4 a, f16x4 b) {
  f16x8 r;
#pragma unroll
  for (int j = 0; j < 4; ++j) { r[j] = a[j]; r[j + 4] = b[j]; }
  return r;
}

// ---------------- K1: 1x1x1 conv as MFMA GEMM; qkvT[cluster][n][16ch] f16
// B-fragments read DIRECTLY from global x (per-lane, 16-lane coalesced, L3-resident);
// no X LDS staging. W staged in LDS (9 KB).
__global__ __launch_bounds__(256) void k_qkv(const float* __restrict__ x,
                                             const float* __restrict__ w,
                                             ushort* __restrict__ qkvT) {
  const int n0  = blockIdx.x * 64;
  const int oct = blockIdx.y;           // 0..11
  __shared__ __align__(16) ushort wt[64 * 72];     // 9216 B
  const int tid = threadIdx.x;
  const float4* w4 = (const float4*)w;
#pragma unroll
  for (int i = 0; i < 4; ++i) {
    const int idx = tid + i * 256;      // 0..1023
    const int oc = idx >> 4, kq = idx & 15;
    float4 wv = w4[(oct * 64 + oc) * 16 + kq];
    ushort4 o;
    o.x = f2hs(wv.x); o.y = f2hs(wv.y); o.z = f2hs(wv.z); o.w = f2hs(wv.w);
    *(ushort4*)(wt + oc * 72 + kq * 4) = o;
  }
  __syncthreads();

  const int lane = tid & 63;
  const int wq   = tid >> 6;
  const int ln15 = lane & 15;
  const int lq   = lane >> 4;
  const int n    = n0 + wq * 16 + ln15;

  f32x4 acc[4];
#pragma unroll
  for (int i = 0; i < 4; ++i) acc[i] = (f32x4){0.f, 0.f, 0.f, 0.f};

#pragma unroll
  for (int kk = 0; kk < 4; ++kk) {
    const int kb = kk * 4 + lq;         // k-quad index; k = kb*4 + j
    f16x4 b;
#pragma unroll
    for (int j = 0; j < 4; ++j)
      b[j] = (f16)x[(size_t)(kb * 4 + j) * NTOT + n];
#pragma unroll
    for (int mt = 0; mt < 4; ++mt) {
      f16x4 a = *(const f16x4*)(wt + (mt * 16 + ln15) * 72 + kk * 16 + lq * 4);
      acc[mt] = __builtin_amdgcn_mfma_f32_16x16x16f16(a, b, acc[mt], 0, 0, 0);
    }
  }
#pragma unroll
  for (int mt = 0; mt < 4; ++mt) {
    const int cl = oct * 4 + mt;
    ushort4 o;
    o.x = f2hs(acc[mt][0]);
    o.y = f2hs(acc[mt][1]);
    o.z = f2hs(acc[mt][2]);
    o.w = f2hs(acc[mt][3]);
    *(ushort4*)(qkvT + ((size_t)cl * NTOT + n) * 16 + lq * 4) = o;
  }
}

// ---------------- K2: grouped 3x3x3 conv, block-diag implicit GEMM on MFMA K=16.
// Wave covers 4t x 2h x 16w: B-planes cached in regs, reused across dt (2 MFMA/read).
// (round-14 verified version; K=32 pairing reverted after r15/r16 failures)
__global__ __launch_bounds__(256, 4) void k_dwconv(const ushort* __restrict__ qkvT,
                                                   const float* __restrict__ dww,
                                                   ushort* __restrict__ out) {
  const int cl = blockIdx.x;        // 0..47
  const int s  = blockIdx.y;        // 0..127
  const int wsel = s & 3, hsel = (s >> 2) & 7, tsel = s >> 5;
  const int t0 = tsel * 4, h0 = hsel * 8, w0 = wsel * 16;
  __shared__ __align__(16) ushort xh[6 * 10 * 18 * 16];  // 34560 B
  __shared__ __align__(16) ushort at[27 * 64];           //  3456 B [tap][p16][ic4]
  const int tid = threadIdx.x;

  for (int idx = tid; idx < 27 * 64; idx += 256) {
    int tap = idx >> 6;
    int p   = (idx >> 2) & 15;
    int ic  = idx & 3;
    at[idx] = f2hs(dww[(cl * 4 + (p >> 2)) * 432 + ((p & 3) * 4 + ic) * 27 + tap]);
  }
  const ushort* cb = qkvT + (size_t)cl * (NTOT * 16);
  for (int ci = tid; ci < 1080; ci += 256) {
    int W = ci % 18;
    int r = ci / 18;
    int H = r % 10;
    int T = r / 10;
    int Tg = t0 - 1 + T, Hg = h0 - 1 + H, Wg = w0 - 1 + W;
    uint4 d0 = {0, 0, 0, 0}, d1 = {0, 0, 0, 0};
    if ((unsigned)Tg < 16u && (unsigned)Hg < 64u && (unsigned)Wg < 64u) {
      const uint4* src = (const uint4*)(cb + (size_t)(Tg * 4096 + Hg * 64 + Wg) * 16);
      d0 = src[0];
      d1 = src[1];
    }
    const int rot = (W >> 2) & 3;
    uint2* dst = (uint2*)(xh + ci * 16);
    uint2 u0 = {d0.x, d0.y}, u1 = {d0.z, d0.w}, u2 = {d1.x, d1.y}, u3 = {d1.z, d1.w};
    dst[(0 + rot) & 3] = u0;
    dst[(1 + rot) & 3] = u1;
    dst[(2 + rot) & 3] = u2;
    dst[(3 + rot) & 3] = u3;
  }
  __syncthreads();

  const int lane = tid & 63;
  const int wv   = tid >> 6;        // h-pair index: wave covers h = wv*2, wv*2+1
  const int hp   = wv * 2;
  const int ln15 = lane & 15;
  const int lq   = lane >> 4;
  const bool diag = (lq == (ln15 >> 2));
  const ushort* bp[3];
#pragma unroll
  for (int dwp = 0; dwp < 3; ++dwp) {
    const int Wl = ln15 + dwp;
    const int slot = (lq + (Wl >> 2)) & 3;
    bp[dwp] = xh + Wl * 16 + slot * 4;
  }
  const f16x4 z4 = {};

  f32x4 acc[4][2];   // [t][h2]
#pragma unroll
  for (int a = 0; a < 4; ++a)
#pragma unroll
    for (int b = 0; b < 2; ++b) acc[a][b] = (f32x4){0.f, 0.f, 0.f, 0.f};

#pragma unroll
  for (int dh = 0; dh < 3; ++dh) {
#pragma unroll
    for (int dwp = 0; dwp < 3; ++dwp) {
      // cache 6 t-planes x 2 h rows
      f16x4 B[6][2];
#pragma unroll
      for (int tt = 0; tt < 6; ++tt)
#pragma unroll
        for (int h2 = 0; h2 < 2; ++h2)
          B[tt][h2] = *(const f16x4*)(bp[dwp] + (tt * 10 + hp + h2 + dh) * 288);
#pragma unroll
      for (int dt = 0; dt < 3; ++dt) {
        const int tap = (dt * 3 + dh) * 3 + dwp;
        f16x4 a = *(const f16x4*)(at + tap * 64 + ln15 * 4);
        if (!diag) a = z4;
#pragma unroll
        for (int t = 0; t < 4; ++t)
#pragma unroll
          for (int h2 = 0; h2 < 2; ++h2)
            acc[t][h2] = __builtin_amdgcn_mfma_f32_16x16x16f16(a, B[t + dt][h2],
                                                               acc[t][h2], 0, 0, 0);
      }
    }
  }
  const int chbase = cl * 16 + lq * 4;
#pragma unroll
  for (int t = 0; t < 4; ++t)
#pragma unroll
    for (int h2 = 0; h2 < 2; ++h2) {
      const int n = (t0 + t) * 4096 + (h0 + hp + h2) * 64 + w0 + ln15;
#pragma unroll
      for (int r = 0; r < 4; ++r)
        out[(size_t)(chbase + r) * NTOT + n] = f2hs(acc[t][h2][r]);
    }
}

// ---------------- K3: gram via MFMA. S[c][d] = sum_n q[c][n]k[d][n]; + sum q^2,k^2
__global__ __launch_bounds__(256) void k_attn_part(const ushort* __restrict__ dwout,
                                                   float* __restrict__ pS,
                                                   float* __restrict__ pQ,
                                                   float* __restrict__ pK) {
  const int head = blockIdx.y;
  const int chunk = blockIdx.x;   // 0..127, each 512 n
  const int tid = threadIdx.x;
  const ushort* qb = dwout + (size_t)(head * 64) * NTOT;
  const ushort* kb = dwout + (size_t)(256 + head * 64) * NTOT;
  __shared__ __align__(16) ushort lsq[64][76];   // 9728 B, row 152B
  __shared__ __align__(16) ushort lsk[64][76];
  const int lane = tid & 63, wv = tid >> 6;
  const int ln15 = lane & 15, lqd = lane >> 4;
  const int c0 = wv * 16;
  const int sch = tid >> 2, spart = tid & 3;
  f32x4 acc[4];
#pragma unroll
  for (int i = 0; i < 4; ++i) acc[i] = (f32x4){0.f, 0.f, 0.f, 0.f};
  float qq = 0.f, kk = 0.f;

  for (int ph = 0; ph < 8; ++ph) {
    const int nb = chunk * 512 + ph * 64;
    __syncthreads();
#pragma unroll
    for (int i = 0; i < 2; ++i) {
      const int id = tid + i * 256;   // 0..511
      const int ch = id >> 3, n8 = id & 7;
      uint4 qv = *(const uint4*)(qb + (size_t)ch * NTOT + nb + n8 * 8);
      uint4 kv = *(const uint4*)(kb + (size_t)ch * NTOT + nb + n8 * 8);
      *(uint2*)&lsq[ch][n8 * 8]     = (uint2){qv.x, qv.y};
      *(uint2*)&lsq[ch][n8 * 8 + 4] = (uint2){qv.z, qv.w};
      *(uint2*)&lsk[ch][n8 * 8]     = (uint2){kv.x, kv.y};
      *(uint2*)&lsk[ch][n8 * 8 + 4] = (uint2){kv.z, kv.w};
    }
    __syncthreads();
#pragma unroll
    for (int ks = 0; ks < 2; ++ks) {
      f16x4 a0 = *(const f16x4*)&lsq[c0 + ln15][ks * 32 + lqd * 4];
      f16x4 a1 = *(const f16x4*)&lsq[c0 + ln15][ks * 32 + lqd * 4 + 16];
      f16x8 a = cmb(a0, a1);
#pragma unroll
      for (int d = 0; d < 4; ++d) {
        f16x4 b0 = *(const f16x4*)&lsk[d * 16 + ln15][ks * 32 + lqd * 4];
        f16x4 b1 = *(const f16x4*)&lsk[d * 16 + ln15][ks * 32 + lqd * 4 + 16];
        f16x8 b = cmb(b0, b1);
        acc[d] = __builtin_amdgcn_mfma_f32_16x16x32_f16(a, b, acc[d], 0, 0, 0);
      }
    }
#pragma unroll
    for (int j4 = 0; j4 < 4; ++j4) {
      uint2 qv = *(const uint2*)&lsq[sch][spart * 16 + j4 * 4];
      uint2 kv = *(const uint2*)&lsk[sch][spart * 16 + j4 * 4];
      qq = fdot2(qv.x, qv.x, qq); qq = fdot2(qv.y, qv.y, qq);
      kk = fdot2(kv.x, kv.x, kk); kk = fdot2(kv.y, kv.y, kk);
    }
  }
  qq += __shfl_xor(qq, 1); qq += __shfl_xor(qq, 2);
  kk += __shfl_xor(kk, 1); kk += __shfl_xor(kk, 2);
  if (spart == 0) {
    pQ[(head * 128 + chunk) * 64 + sch] = qq;
    pK[(head * 128 + chunk) * 64 + sch] = kk;
  }
  float* ps = pS + (size_t)(head * 128 + chunk) * 4096;
#pragma unroll
  for (int d = 0; d < 4; ++d)
#pragma unroll
    for (int r = 0; r < 4; ++r)
      ps[(c0 + lqd * 4 + r) * 64 + d * 16 + ln15] = acc[d][r];
}

// ---------------- K4a: reduce partials, normalize, temperature, softmax -> A[h][c][d]
__global__ __launch_bounds__(256) void k_softmax(const float* __restrict__ pS,
                                                 const float* __restrict__ pQ,
                                                 const float* __restrict__ pK,
                                                 const float* __restrict__ temp,
                                                 float* __restrict__ A) {
  const int head = blockIdx.x;
  const int tid = threadIdx.x;
  __shared__ float rq[64], rk[64];
  if (tid < 64) {
    float s = 0.f;
    for (int ch = 0; ch < 128; ++ch) s += pQ[(head * 128 + ch) * 64 + tid];
    rq[tid] = 1.f / fmaxf(sqrtf(s), 1e-12f);
  } else if (tid < 128) {
    float s = 0.f;
    for (int ch = 0; ch < 128; ++ch) s += pK[(head * 128 + ch) * 64 + (tid - 64)];
    rk[tid - 64] = 1.f / fmaxf(sqrtf(s), 1e-12f);
  }
  __syncthreads();
  const int c = tid >> 2, r = tid & 3;
  float4 a0 = {0,0,0,0}, a1 = {0,0,0,0}, a2 = {0,0,0,0}, a3 = {0,0,0,0};
  const float* base = pS + head * 128 * 4096 + c * 64 + r * 16;
  for (int ch = 0; ch < 128; ++ch) {
    const float* p = base + ch * 4096;
    float4 b0 = *(const float4*)(p + 0);
    float4 b1 = *(const float4*)(p + 4);
    float4 b2 = *(const float4*)(p + 8);
    float4 b3 = *(const float4*)(p + 12);
    a0.x += b0.x; a0.y += b0.y; a0.z += b0.z; a0.w += b0.w;
    a1.x += b1.x; a1.y += b1.y; a1.z += b1.z; a1.w += b1.w;
    a2.x += b2.x; a2.y += b2.y; a2.z += b2.z; a2.w += b2.w;
    a3.x += b3.x; a3.y += b3.y; a3.z += b3.z; a3.w += b3.w;
  }
  float v[16] = {a0.x, a0.y, a0.z, a0.w, a1.x, a1.y, a1.z, a1.w,
                 a2.x, a2.y, a2.z, a2.w, a3.x, a3.y, a3.z, a3.w};
  const float tmp = temp[head];
  const float rqc = rq[c];
#pragma unroll
  for (int dd = 0; dd < 16; ++dd) v[dd] = v[dd] * rqc * rk[r * 16 + dd] * tmp;
  float m = v[0];
#pragma unroll
  for (int dd = 1; dd < 16; ++dd) m = fmaxf(m, v[dd]);
  m = fmaxf(m, __shfl_xor(m, 1));
  m = fmaxf(m, __shfl_xor(m, 2));
  float s = 0.f;
#pragma unroll
  for (int dd = 0; dd < 16; ++dd) { v[dd] = expf(v[dd] - m); s += v[dd]; }
  s += __shfl_xor(s, 1);
  s += __shfl_xor(s, 2);
  const float inv = 1.f / s;
  float* ao = A + head * 4096 + c * 64 + r * 16;
#pragma unroll
  for (int q4 = 0; q4 < 4; ++q4) {
    float4 o = make_float4(v[q4*4+0]*inv, v[q4*4+1]*inv, v[q4*4+2]*inv, v[q4*4+3]*inv);
    *(float4*)(ao + q4 * 4) = o;
  }
}

// ---------------- K4b: MtT[oc][h*64+d] = sum_c pw[oc][h*64+c]*A[h][c][d]  (f16)
__global__ __launch_bounds__(64) void k_mt(const float* __restrict__ pw,
                                           const float* __restrict__ A,
                                           ushort* __restrict__ MtT) {
  const int hd = blockIdx.x;   // 0..255
  const int h = hd >> 6, d = hd & 63;
  const int oc = threadIdx.x;  // 0..63
  float s = 0.f;
  for (int c = 0; c < 64; ++c)
    s = fmaf(pw[oc * 256 + h * 64 + c], A[(h * 64 + c) * 64 + d], s);
  MtT[oc * 256 + hd] = f2hs(s);
}

// ---------------- K5: y[oc][n] = sum_hd MtT[oc][hd] * v[hd][n]  via MFMA
__global__ __launch_bounds__(256) void k_pv(const ushort* __restrict__ dwout,
                                            const ushort* __restrict__ MtT,
                                            float* __restrict__ y) {
  const int n0 = blockIdx.x * 64;
  const ushort* vb = dwout + 512 * (size_t)NTOT;
  __shared__ __align__(16) ushort vt[64 * 256];   // 32 KB: [n][hd] quad-rotated
  const int tid = threadIdx.x;
#pragma unroll
  for (int i = 0; i < 2; ++i) {
    const int id = tid + i * 256;    // 0..511
    const int kq = id >> 3;          // hd-quad 0..63
    const int ng = id & 7;           // n-octet
    uint4 r0 = *(const uint4*)(vb + (size_t)(kq * 4 + 0) * NTOT + n0 + ng * 8);
    uint4 r1 = *(const uint4*)(vb + (size_t)(kq * 4 + 1) * NTOT + n0 + ng * 8);
    uint4 r2 = *(const uint4*)(vb + (size_t)(kq * 4 + 2) * NTOT + n0 + ng * 8);
    uint4 r3 = *(const uint4*)(vb + (size_t)(kq * 4 + 3) * NTOT + n0 + ng * 8);
    const ushort* h0 = (const ushort*)&r0;
    const ushort* h1 = (const ushort*)&r1;
    const ushort* h2 = (const ushort*)&r2;
    const ushort* h3 = (const ushort*)&r3;
#pragma unroll
    for (int j = 0; j < 8; ++j) {
      const int n = ng * 8 + j;
      unsigned lo = (unsigned)h0[j] | ((unsigned)h1[j] << 16);
      unsigned hi = (unsigned)h2[j] | ((unsigned)h3[j] << 16);
      const int slot = (kq + n + (n >> 3)) & 63;
      *(uint2*)(vt + n * 256 + slot * 4) = (uint2){lo, hi};
    }
  }
  __syncthreads();

  const int lane = tid & 63;
  const int wv   = tid >> 6;
  const int ln15 = lane & 15, lq = lane >> 4;
  const int nloc = wv * 16 + ln15;
  const int nrot = nloc + (nloc >> 3);

  f32x4 acc[4];
#pragma unroll
  for (int i = 0; i < 4; ++i) acc[i] = (f32x4){0.f, 0.f, 0.f, 0.f};

#pragma unroll
  for (int kb = 0; kb < 8; ++kb) {
    const int kq0 = kb * 8 + lq;
    const int s0 = ((kq0 + nrot) & 63) * 4;
    const int s1 = ((kq0 + 4 + nrot) & 63) * 4;
    f16x4 b0 = *(const f16x4*)(vt + nloc * 256 + s0);
    f16x4 b1 = *(const f16x4*)(vt + nloc * 256 + s1);
    f16x8 b = cmb(b0, b1);
#pragma unroll
    for (int mt = 0; mt < 4; ++mt) {
      const ushort* ap = MtT + (mt * 16 + ln15) * 256 + kb * 32 + lq * 4;
      f16x4 a0 = *(const f16x4*)(ap);
      f16x4 a1 = *(const f16x4*)(ap + 16);
      f16x8 a = cmb(a0, a1);
      acc[mt] = __builtin_amdgcn_mfma_f32_16x16x32_f16(a, b, acc[mt], 0, 0, 0);
    }
  }
  const int n = n0 + nloc;
#pragma unroll
  for (int mt = 0; mt < 4; ++mt) {
    const int oc = mt * 16 + lq * 4;
#pragma unroll
    for (int r = 0; r < 4; ++r)
      y[(size_t)(oc + r) * NTOT + n] = acc[mt][r];
  }
}

extern "C" void kernel_launch(void* const* d_in, const int* in_sizes, int n_in,
                              void* d_out, int out_size, void* d_ws, size_t ws_size,
                              hipStream_t stream) {
  const float* x      = (const float*)d_in[0];
  const float* qkv_w  = (const float*)d_in[1];
  const float* dw_w   = (const float*)d_in[2];
  const float* proj_w = (const float*)d_in[3];
  const float* temp   = (const float*)d_in[4];
  float* out = (float*)d_out;

  char* w8 = (char*)d_ws;
  ushort* qkvT = (ushort*)(w8);                        // [48][65536][16] f16 = 100,663,296 B
  ushort* dwout = (ushort*)(w8 + 100663296ull);        // [768][n] f16 = 100,663,296 B
  float* pS    = (float*)(w8 + 201326592ull);          // 4*128*4096 f32 = 8,388,608 B
  float* pQ    = (float*)(w8 + 209715200ull);          // 32768 f32
  float* pK    = (float*)(w8 + 209846272ull);          // 32768 f32
  float* A     = (float*)(w8 + 209977344ull);          // 16384 f32
  ushort* MtT  = (ushort*)(w8 + 210042880ull);         // 64*256 f16 = 32768 B
  // total ~210 MB

  k_qkv<<<dim3(1024, 12), 256, 0, stream>>>(x, qkv_w, qkvT);
  k_dwconv<<<dim3(48, 128), 256, 0, stream>>>(qkvT, dw_w, dwout);
  k_attn_part<<<dim3(128, 4), 256, 0, stream>>>(dwout, pS, pQ, pK);
  k_softmax<<<4, 256, 0, stream>>>(pS, pQ, pK, temp, A);
  k_mt<<<256, 64, 0, stream>>>(proj_w, A, MtT);
  k_pv<<<1024, 256, 0, stream>>>(dwout, MtT, out);
}

// Round 18
// 150.413 us; speedup vs baseline: 2.7595x; 1.2279x over previous
//
#include <hip/hip_runtime.h>
#include <hip/hip_bf16.h>
#include <hip/hip_fp16.h>

#define NTOT 65536   // T*H*W

typedef __hip_bfloat16 bf16;
typedef _Float16 f16;
typedef f16 f16x4 __attribute__((ext_vector_type(4)));
typedef f16 f16x8 __attribute__((ext_vector_type(8)));
typedef float f32x4 __attribute__((ext_vector_type(4)));
typedef _Float16 h2f16 __attribute__((ext_vector_type(2)));

__device__ __forceinline__ ushort f2hs(float f) {
  __half h = __float2half(f);
  return __half_as_ushort(h);
}
__device__ __forceinline__ float fdot2(unsigned a, unsigned b, float c) {
  return __builtin_amdgcn_fdot2(__builtin_bit_cast(h2f16, a),
                                __builtin_bit_cast(h2f16, b), c, false);
}
__device__ __forceinline__ f16x8 cmb(f16x4 a, f16x4 b) {
  f16x8 r;
#pragma unroll
  for (int j = 0; j < 4; ++j) { r[j] = a[j]; r[j + 4] = b[j]; }
  return r;
}

// ---------------- K1: 1x1x1 conv as MFMA GEMM; qkvT[cluster][n][16ch] f16
// B-fragments read DIRECTLY from global x (per-lane, 16-lane coalesced, L3-resident).
__global__ __launch_bounds__(256) void k_qkv(const float* __restrict__ x,
                                             const float* __restrict__ w,
                                             ushort* __restrict__ qkvT) {
  const int n0  = blockIdx.x * 64;
  const int oct = blockIdx.y;           // 0..11
  __shared__ __align__(16) ushort wt[64 * 72];     // 9216 B
  const int tid = threadIdx.x;
  const float4* w4 = (const float4*)w;
#pragma unroll
  for (int i = 0; i < 4; ++i) {
    const int idx = tid + i * 256;      // 0..1023
    const int oc = idx >> 4, kq = idx & 15;
    float4 wv = w4[(oct * 64 + oc) * 16 + kq];
    ushort4 o;
    o.x = f2hs(wv.x); o.y = f2hs(wv.y); o.z = f2hs(wv.z); o.w = f2hs(wv.w);
    *(ushort4*)(wt + oc * 72 + kq * 4) = o;
  }
  __syncthreads();

  const int lane = tid & 63;
  const int wq   = tid >> 6;
  const int ln15 = lane & 15;
  const int lq   = lane >> 4;
  const int n    = n0 + wq * 16 + ln15;

  f32x4 acc[4];
#pragma unroll
  for (int i = 0; i < 4; ++i) acc[i] = (f32x4){0.f, 0.f, 0.f, 0.f};

#pragma unroll
  for (int kk = 0; kk < 4; ++kk) {
    const int kb = kk * 4 + lq;         // k-quad index; k = kb*4 + j
    f16x4 b;
#pragma unroll
    for (int j = 0; j < 4; ++j)
      b[j] = (f16)x[(size_t)(kb * 4 + j) * NTOT + n];
#pragma unroll
    for (int mt = 0; mt < 4; ++mt) {
      f16x4 a = *(const f16x4*)(wt + (mt * 16 + ln15) * 72 + kk * 16 + lq * 4);
      acc[mt] = __builtin_amdgcn_mfma_f32_16x16x16f16(a, b, acc[mt], 0, 0, 0);
    }
  }
#pragma unroll
  for (int mt = 0; mt < 4; ++mt) {
    const int cl = oct * 4 + mt;
    ushort4 o;
    o.x = f2hs(acc[mt][0]);
    o.y = f2hs(acc[mt][1]);
    o.z = f2hs(acc[mt][2]);
    o.w = f2hs(acc[mt][3]);
    *(ushort4*)(qkvT + ((size_t)cl * NTOT + n) * 16 + lq * 4) = o;
  }
}

// ---------------- K2: grouped 3x3x3 conv, block-diag implicit GEMM on MFMA K=16.
// Wave covers 4t x 2h x 16w: B-planes cached in regs, reused across dt (2 MFMA/read).
__global__ __launch_bounds__(256, 4) void k_dwconv(const ushort* __restrict__ qkvT,
                                                   const float* __restrict__ dww,
                                                   ushort* __restrict__ out) {
  const int cl = blockIdx.x;        // 0..47
  const int s  = blockIdx.y;        // 0..127
  const int wsel = s & 3, hsel = (s >> 2) & 7, tsel = s >> 5;
  const int t0 = tsel * 4, h0 = hsel * 8, w0 = wsel * 16;
  __shared__ __align__(16) ushort xh[6 * 10 * 18 * 16];  // 34560 B
  __shared__ __align__(16) ushort at[27 * 64];           //  3456 B [tap][p16][ic4]
  const int tid = threadIdx.x;

  for (int idx = tid; idx < 27 * 64; idx += 256) {
    int tap = idx >> 6;
    int p   = (idx >> 2) & 15;
    int ic  = idx & 3;
    at[idx] = f2hs(dww[(cl * 4 + (p >> 2)) * 432 + ((p & 3) * 4 + ic) * 27 + tap]);
  }
  const ushort* cb = qkvT + (size_t)cl * (NTOT * 16);
  for (int ci = tid; ci < 1080; ci += 256) {
    int W = ci % 18;
    int r = ci / 18;
    int H = r % 10;
    int T = r / 10;
    int Tg = t0 - 1 + T, Hg = h0 - 1 + H, Wg = w0 - 1 + W;
    uint4 d0 = {0, 0, 0, 0}, d1 = {0, 0, 0, 0};
    if ((unsigned)Tg < 16u && (unsigned)Hg < 64u && (unsigned)Wg < 64u) {
      const uint4* src = (const uint4*)(cb + (size_t)(Tg * 4096 + Hg * 64 + Wg) * 16);
      d0 = src[0];
      d1 = src[1];
    }
    const int rot = (W >> 2) & 3;
    uint2* dst = (uint2*)(xh + ci * 16);
    uint2 u0 = {d0.x, d0.y}, u1 = {d0.z, d0.w}, u2 = {d1.x, d1.y}, u3 = {d1.z, d1.w};
    dst[(0 + rot) & 3] = u0;
    dst[(1 + rot) & 3] = u1;
    dst[(2 + rot) & 3] = u2;
    dst[(3 + rot) & 3] = u3;
  }
  __syncthreads();

  const int lane = tid & 63;
  const int wv   = tid >> 6;        // h-pair index: wave covers h = wv*2, wv*2+1
  const int hp   = wv * 2;
  const int ln15 = lane & 15;
  const int lq   = lane >> 4;
  const bool diag = (lq == (ln15 >> 2));
  const ushort* bp[3];
#pragma unroll
  for (int dwp = 0; dwp < 3; ++dwp) {
    const int Wl = ln15 + dwp;
    const int slot = (lq + (Wl >> 2)) & 3;
    bp[dwp] = xh + Wl * 16 + slot * 4;
  }
  const f16x4 z4 = {};

  f32x4 acc[4][2];   // [t][h2]
#pragma unroll
  for (int a = 0; a < 4; ++a)
#pragma unroll
    for (int b = 0; b < 2; ++b) acc[a][b] = (f32x4){0.f, 0.f, 0.f, 0.f};

#pragma unroll
  for (int dh = 0; dh < 3; ++dh) {
#pragma unroll
    for (int dwp = 0; dwp < 3; ++dwp) {
      // cache 6 t-planes x 2 h rows
      f16x4 B[6][2];
#pragma unroll
      for (int tt = 0; tt < 6; ++tt)
#pragma unroll
        for (int h2 = 0; h2 < 2; ++h2)
          B[tt][h2] = *(const f16x4*)(bp[dwp] + (tt * 10 + hp + h2 + dh) * 288);
#pragma unroll
      for (int dt = 0; dt < 3; ++dt) {
        const int tap = (dt * 3 + dh) * 3 + dwp;
        f16x4 a = *(const f16x4*)(at + tap * 64 + ln15 * 4);
        if (!diag) a = z4;
#pragma unroll
        for (int t = 0; t < 4; ++t)
#pragma unroll
          for (int h2 = 0; h2 < 2; ++h2)
            acc[t][h2] = __builtin_amdgcn_mfma_f32_16x16x16f16(a, B[t + dt][h2],
                                                               acc[t][h2], 0, 0, 0);
      }
    }
  }
  const int chbase = cl * 16 + lq * 4;
#pragma unroll
  for (int t = 0; t < 4; ++t)
#pragma unroll
    for (int h2 = 0; h2 < 2; ++h2) {
      const int n = (t0 + t) * 4096 + (h0 + hp + h2) * 64 + w0 + ln15;
#pragma unroll
      for (int r = 0; r < 4; ++r)
        out[(size_t)(chbase + r) * NTOT + n] = f2hs(acc[t][h2][r]);
    }
}

// ---------------- K3: gram via MFMA. S[c][d] = sum_n q[c][n]k[d][n]; + sum q^2,k^2
__global__ __launch_bounds__(256) void k_attn_part(const ushort* __restrict__ dwout,
                                                   float* __restrict__ pS,
                                                   float* __restrict__ pQ,
                                                   float* __restrict__ pK) {
  const int head = blockIdx.y;
  const int chunk = blockIdx.x;   // 0..127, each 512 n
  const int tid = threadIdx.x;
  const ushort* qb = dwout + (size_t)(head * 64) * NTOT;
  const ushort* kb = dwout + (size_t)(256 + head * 64) * NTOT;
  __shared__ __align__(16) ushort lsq[64][76];   // 9728 B, row 152B
  __shared__ __align__(16) ushort lsk[64][76];
  const int lane = tid & 63, wv = tid >> 6;
  const int ln15 = lane & 15, lqd = lane >> 4;
  const int c0 = wv * 16;
  const int sch = tid >> 2, spart = tid & 3;
  f32x4 acc[4];
#pragma unroll
  for (int i = 0; i < 4; ++i) acc[i] = (f32x4){0.f, 0.f, 0.f, 0.f};
  float qq = 0.f, kk = 0.f;

  for (int ph = 0; ph < 8; ++ph) {
    const int nb = chunk * 512 + ph * 64;
    __syncthreads();
#pragma unroll
    for (int i = 0; i < 2; ++i) {
      const int id = tid + i * 256;   // 0..511
      const int ch = id >> 3, n8 = id & 7;
      uint4 qv = *(const uint4*)(qb + (size_t)ch * NTOT + nb + n8 * 8);
      uint4 kv = *(const uint4*)(kb + (size_t)ch * NTOT + nb + n8 * 8);
      *(uint2*)&lsq[ch][n8 * 8]     = (uint2){qv.x, qv.y};
      *(uint2*)&lsq[ch][n8 * 8 + 4] = (uint2){qv.z, qv.w};
      *(uint2*)&lsk[ch][n8 * 8]     = (uint2){kv.x, kv.y};
      *(uint2*)&lsk[ch][n8 * 8 + 4] = (uint2){kv.z, kv.w};
    }
    __syncthreads();
#pragma unroll
    for (int ks = 0; ks < 2; ++ks) {
      f16x4 a0 = *(const f16x4*)&lsq[c0 + ln15][ks * 32 + lqd * 4];
      f16x4 a1 = *(const f16x4*)&lsq[c0 + ln15][ks * 32 + lqd * 4 + 16];
      f16x8 a = cmb(a0, a1);
#pragma unroll
      for (int d = 0; d < 4; ++d) {
        f16x4 b0 = *(const f16x4*)&lsk[d * 16 + ln15][ks * 32 + lqd * 4];
        f16x4 b1 = *(const f16x4*)&lsk[d * 16 + ln15][ks * 32 + lqd * 4 + 16];
        f16x8 b = cmb(b0, b1);
        acc[d] = __builtin_amdgcn_mfma_f32_16x16x32_f16(a, b, acc[d], 0, 0, 0);
      }
    }
#pragma unroll
    for (int j4 = 0; j4 < 4; ++j4) {
      uint2 qv = *(const uint2*)&lsq[sch][spart * 16 + j4 * 4];
      uint2 kv = *(const uint2*)&lsk[sch][spart * 16 + j4 * 4];
      qq = fdot2(qv.x, qv.x, qq); qq = fdot2(qv.y, qv.y, qq);
      kk = fdot2(kv.x, kv.x, kk); kk = fdot2(kv.y, kv.y, kk);
    }
  }
  qq += __shfl_xor(qq, 1); qq += __shfl_xor(qq, 2);
  kk += __shfl_xor(kk, 1); kk += __shfl_xor(kk, 2);
  if (spart == 0) {
    pQ[(head * 128 + chunk) * 64 + sch] = qq;
    pK[(head * 128 + chunk) * 64 + sch] = kk;
  }
  float* ps = pS + (size_t)(head * 128 + chunk) * 4096;
#pragma unroll
  for (int d = 0; d < 4; ++d)
#pragma unroll
    for (int r = 0; r < 4; ++r)
      ps[(c0 + lqd * 4 + r) * 64 + d * 16 + ln15] = acc[d][r];
}

// ---------------- K4a: parallel reduce+softmax. Grid (64 c, 4 heads), 256 thr.
// Each block handles one (head, c) row: reduces pS/pQ/pK partials, softmax -> A.
__global__ __launch_bounds__(256) void k_softmax(const float* __restrict__ pS,
                                                 const float* __restrict__ pQ,
                                                 const float* __restrict__ pK,
                                                 const float* __restrict__ temp,
                                                 float* __restrict__ A) {
  const int c    = blockIdx.x;    // 0..63
  const int head = blockIdx.y;    // 0..3
  const int tid  = threadIdx.x;
  const int d    = tid & 63, part = tid >> 6;
  __shared__ float red[4][64];
  __shared__ float rq2[128];
  __shared__ float rk[64];
  __shared__ float rqs;

  // rk[d] = 1/max(sqrt(sum_ch pK[head][ch][d]), eps)
  {
    float s = 0.f;
    for (int ch = part * 32; ch < part * 32 + 32; ++ch)
      s += pK[(head * 128 + ch) * 64 + d];
    red[part][d] = s;
  }
  // rq partial: threads 0..127 read pQ for this c
  if (tid < 128) rq2[tid] = pQ[(head * 128 + tid) * 64 + c];
  __syncthreads();
  if (tid < 64) {
    float s = red[0][tid] + red[1][tid] + red[2][tid] + red[3][tid];
    rk[tid] = 1.f / fmaxf(sqrtf(s), 1e-12f);
  }
  if (tid >= 64 && tid < 128) {
    // wave 1 (threads 64..127): reduce rq2[0..127]
    float s = rq2[tid - 64] + rq2[tid];   // pairwise: [0..63]+[64..127]
#pragma unroll
    for (int o = 1; o <= 32; o <<= 1) s += __shfl_xor(s, o);
    if (tid == 64) rqs = 1.f / fmaxf(sqrtf(s), 1e-12f);
  }
  __syncthreads();

  // S row reduce: red[part][d] = sum of 32 chunks of pS[head][ch][c][d]
  {
    float s = 0.f;
    for (int ch = part * 32; ch < part * 32 + 32; ++ch)
      s += pS[(size_t)(head * 128 + ch) * 4096 + c * 64 + d];
    red[part][d] = s;
  }
  __syncthreads();
  if (tid < 64) {
    const float Sd = red[0][tid] + red[1][tid] + red[2][tid] + red[3][tid];
    float v = Sd * rqs * rk[tid] * temp[head];
    float m = v;
#pragma unroll
    for (int o = 1; o <= 32; o <<= 1) m = fmaxf(m, __shfl_xor(m, o));
    float e = expf(v - m);
    float s = e;
#pragma unroll
    for (int o = 1; o <= 32; o <<= 1) s += __shfl_xor(s, o);
    A[head * 4096 + c * 64 + tid] = e / s;
  }
}

// ---------------- K4b: MtT[oc][h*64+d] = sum_c pw[oc][h*64+c]*A[h][c][d]  (f16)
__global__ __launch_bounds__(64) void k_mt(const float* __restrict__ pw,
                                           const float* __restrict__ A,
                                           ushort* __restrict__ MtT) {
  const int hd = blockIdx.x;   // 0..255
  const int h = hd >> 6, d = hd & 63;
  const int oc = threadIdx.x;  // 0..63
  float s = 0.f;
  for (int c = 0; c < 64; ++c)
    s = fmaf(pw[oc * 256 + h * 64 + c], A[(h * 64 + c) * 64 + d], s);
  MtT[oc * 256 + hd] = f2hs(s);
}

// ---------------- K5: y[oc][n] = sum_hd MtT[oc][hd] * v[hd][n]  via MFMA
__global__ __launch_bounds__(256) void k_pv(const ushort* __restrict__ dwout,
                                            const ushort* __restrict__ MtT,
                                            float* __restrict__ y) {
  const int n0 = blockIdx.x * 64;
  const ushort* vb = dwout + 512 * (size_t)NTOT;
  __shared__ __align__(16) ushort vt[64 * 256];   // 32 KB: [n][hd] quad-rotated
  const int tid = threadIdx.x;
#pragma unroll
  for (int i = 0; i < 2; ++i) {
    const int id = tid + i * 256;    // 0..511
    const int kq = id >> 3;          // hd-quad 0..63
    const int ng = id & 7;           // n-octet
    uint4 r0 = *(const uint4*)(vb + (size_t)(kq * 4 + 0) * NTOT + n0 + ng * 8);
    uint4 r1 = *(const uint4*)(vb + (size_t)(kq * 4 + 1) * NTOT + n0 + ng * 8);
    uint4 r2 = *(const uint4*)(vb + (size_t)(kq * 4 + 2) * NTOT + n0 + ng * 8);
    uint4 r3 = *(const uint4*)(vb + (size_t)(kq * 4 + 3) * NTOT + n0 + ng * 8);
    const ushort* h0 = (const ushort*)&r0;
    const ushort* h1 = (const ushort*)&r1;
    const ushort* h2 = (const ushort*)&r2;
    const ushort* h3 = (const ushort*)&r3;
#pragma unroll
    for (int j = 0; j < 8; ++j) {
      const int n = ng * 8 + j;
      unsigned lo = (unsigned)h0[j] | ((unsigned)h1[j] << 16);
      unsigned hi = (unsigned)h2[j] | ((unsigned)h3[j] << 16);
      const int slot = (kq + n + (n >> 3)) & 63;
      *(uint2*)(vt + n * 256 + slot * 4) = (uint2){lo, hi};
    }
  }
  __syncthreads();

  const int lane = tid & 63;
  const int wv   = tid >> 6;
  const int ln15 = lane & 15, lq = lane >> 4;
  const int nloc = wv * 16 + ln15;
  const int nrot = nloc + (nloc >> 3);

  f32x4 acc[4];
#pragma unroll
  for (int i = 0; i < 4; ++i) acc[i] = (f32x4){0.f, 0.f, 0.f, 0.f};

#pragma unroll
  for (int kb = 0; kb < 8; ++kb) {
    const int kq0 = kb * 8 + lq;
    const int s0 = ((kq0 + nrot) & 63) * 4;
    const int s1 = ((kq0 + 4 + nrot) & 63) * 4;
    f16x4 b0 = *(const f16x4*)(vt + nloc * 256 + s0);
    f16x4 b1 = *(const f16x4*)(vt + nloc * 256 + s1);
    f16x8 b = cmb(b0, b1);
#pragma unroll
    for (int mt = 0; mt < 4; ++mt) {
      const ushort* ap = MtT + (mt * 16 + ln15) * 256 + kb * 32 + lq * 4;
      f16x4 a0 = *(const f16x4*)(ap);
      f16x4 a1 = *(const f16x4*)(ap + 16);
      f16x8 a = cmb(a0, a1);
      acc[mt] = __builtin_amdgcn_mfma_f32_16x16x32_f16(a, b, acc[mt], 0, 0, 0);
    }
  }
  const int n = n0 + nloc;
#pragma unroll
  for (int mt = 0; mt < 4; ++mt) {
    const int oc = mt * 16 + lq * 4;
#pragma unroll
    for (int r = 0; r < 4; ++r)
      y[(size_t)(oc + r) * NTOT + n] = acc[mt][r];
  }
}

extern "C" void kernel_launch(void* const* d_in, const int* in_sizes, int n_in,
                              void* d_out, int out_size, void* d_ws, size_t ws_size,
                              hipStream_t stream) {
  const float* x      = (const float*)d_in[0];
  const float* qkv_w  = (const float*)d_in[1];
  const float* dw_w   = (const float*)d_in[2];
  const float* proj_w = (const float*)d_in[3];
  const float* temp   = (const float*)d_in[4];
  float* out = (float*)d_out;

  char* w8 = (char*)d_ws;
  ushort* qkvT = (ushort*)(w8);                        // [48][65536][16] f16 = 100,663,296 B
  ushort* dwout = (ushort*)(w8 + 100663296ull);        // [768][n] f16 = 100,663,296 B
  float* pS    = (float*)(w8 + 201326592ull);          // 4*128*4096 f32 = 8,388,608 B
  float* pQ    = (float*)(w8 + 209715200ull);          // 32768 f32
  float* pK    = (float*)(w8 + 209846272ull);          // 32768 f32
  float* A     = (float*)(w8 + 209977344ull);          // 16384 f32
  ushort* MtT  = (ushort*)(w8 + 210042880ull);         // 64*256 f16 = 32768 B
  // total ~210 MB

  k_qkv<<<dim3(1024, 12), 256, 0, stream>>>(x, qkv_w, qkvT);
  k_dwconv<<<dim3(48, 128), 256, 0, stream>>>(qkvT, dw_w, dwout);
  k_attn_part<<<dim3(128, 4), 256, 0, stream>>>(dwout, pS, pQ, pK);
  k_softmax<<<dim3(64, 4), 256, 0, stream>>>(pS, pQ, pK, temp, A);
  k_mt<<<256, 64, 0, stream>>>(proj_w, A, MtT);
  k_pv<<<1024, 256, 0, stream>>>(dwout, MtT, out);
}